// Round 6
// baseline (13925.682 us; speedup 1.0000x reference)
//
#include <hip/hip_runtime.h>
#include <hip/hip_fp16.h>
#include <math.h>

// Problem constants
#define KDIM  2048
// d_out layout (floats): y | k | v
#define Y_OFF 0
#define K_OFF 8388608
#define V_OFF 16777216

// ---------------------------------------------------------------------------
// Kernel 1: qkv = x @ Wc^T + bc, fused with rope-scale + scatter.
// 8x8 per-thread tile, BM=BN=128, BK=16, double-buffered LDS (1 barrier/tile).
// q is written COMPACT (64 dims) pre-multiplied by 2.0 (exact).
// Accumulation: per-output single fp32 acc, strictly ascending k (unchanged
// numeric class vs R5 which passed at absmax 32 / threshold 297).
// ---------------------------------------------------------------------------
__global__ __launch_bounds__(256, 4) void gemm_rope_kernel(
    const float* __restrict__ x, const float* __restrict__ Wc,
    const float* __restrict__ bc, const float* __restrict__ fq,
    float* __restrict__ qws, float* __restrict__ out)
{
    // k-major, pad 132 (132 mod 32 == 4): staging writes 2-way (free),
    // frag reads broadcast/2-way (free).
    __shared__ __align__(16) float As[2][16][132];
    __shared__ __align__(16) float Bs[2][16][132];

    const int t  = threadIdx.x;
    const int bx = blockIdx.x;   // col tile 0..31 (reduced cols)
    const int by = blockIdx.y;   // row tile 0..31
    const int tx = t & 15, ty = t >> 4;

    // staging mapping: thread -> (row srow_, row+64), k-chunk skc
    const int srow_ = t >> 2;        // 0..63
    const int skc   = (t & 3) << 2;  // 0,4,8,12

    // B source rows (fixed per thread)
    int bsrc[2];
    #pragma unroll
    for (int p = 0; p < 2; ++p) {
        const int c = bx * 128 + srow_ + (p << 6);
        int sr;
        if (c < 1024)      sr = ((c >> 6) << 7) + (c & 63);
        else if (c < 2048) sr = 2048 + (((c - 1024) >> 6) << 7) + (c & 63);
        else               sr = 4096 + (c - 2048);
        bsrc[p] = sr;
    }
    const int arow0 = by * 128 + srow_;

    float acc[8][8];
    #pragma unroll
    for (int i = 0; i < 8; ++i)
        #pragma unroll
        for (int j = 0; j < 8; ++j) acc[i][j] = 0.f;

    // ---- stage tile 0 into buffer 0
    #pragma unroll
    for (int p = 0; p < 2; ++p) {
        float4 va = *(const float4*)(x + (size_t)(arow0 + (p << 6)) * KDIM + skc);
        As[0][skc + 0][srow_ + (p << 6)] = va.x;
        As[0][skc + 1][srow_ + (p << 6)] = va.y;
        As[0][skc + 2][srow_ + (p << 6)] = va.z;
        As[0][skc + 3][srow_ + (p << 6)] = va.w;
        float4 vb = *(const float4*)(Wc + (size_t)bsrc[p] * KDIM + skc);
        Bs[0][skc + 0][srow_ + (p << 6)] = vb.x;
        Bs[0][skc + 1][srow_ + (p << 6)] = vb.y;
        Bs[0][skc + 2][srow_ + (p << 6)] = vb.z;
        Bs[0][skc + 3][srow_ + (p << 6)] = vb.w;
    }
    __syncthreads();

    for (int kt = 0; kt < 128; ++kt) {
        const int cur = kt & 1;

        // ---- prefetch next K-tile into registers (latency hides under FMA)
        float4 pa[2], pb[2];
        if (kt < 127) {
            const int kn = (kt + 1) << 4;
            #pragma unroll
            for (int p = 0; p < 2; ++p) {
                pa[p] = *(const float4*)(x  + (size_t)(arow0 + (p << 6)) * KDIM + kn + skc);
                pb[p] = *(const float4*)(Wc + (size_t)bsrc[p] * KDIM + kn + skc);
            }
        }

        // ---- compute 16 kk on current buffer
        #pragma unroll
        for (int kk = 0; kk < 16; ++kk) {
            float4 a0 = *(const float4*)(&As[cur][kk][ty << 3]);
            float4 a1 = *(const float4*)(&As[cur][kk][(ty << 3) + 4]);
            float4 b0 = *(const float4*)(&Bs[cur][kk][tx << 2]);
            float4 b1 = *(const float4*)(&Bs[cur][kk][64 + (tx << 2)]);
            const float av[8] = {a0.x, a0.y, a0.z, a0.w, a1.x, a1.y, a1.z, a1.w};
            const float bv[8] = {b0.x, b0.y, b0.z, b0.w, b1.x, b1.y, b1.z, b1.w};
            #pragma unroll
            for (int i = 0; i < 8; ++i)
                #pragma unroll
                for (int j = 0; j < 8; ++j)
                    acc[i][j] = fmaf(av[i], bv[j], acc[i][j]);
        }

        // ---- commit prefetch to the other buffer; one barrier per tile
        if (kt < 127) {
            const int nxt = cur ^ 1;
            #pragma unroll
            for (int p = 0; p < 2; ++p) {
                const int r = srow_ + (p << 6);
                As[nxt][skc + 0][r] = pa[p].x;
                As[nxt][skc + 1][r] = pa[p].y;
                As[nxt][skc + 2][r] = pa[p].z;
                As[nxt][skc + 3][r] = pa[p].w;
                Bs[nxt][skc + 0][r] = pb[p].x;
                Bs[nxt][skc + 1][r] = pb[p].y;
                Bs[nxt][skc + 2][r] = pb[p].z;
                Bs[nxt][skc + 3][r] = pb[p].w;
            }
            __syncthreads();
        }
    }

    // ---- epilogue: bias + rope-scale + scatter
    float* kout = out + K_OFF;
    float* vout = out + V_OFF;
    #pragma unroll
    for (int i = 0; i < 8; ++i) {
        const int r = by * 128 + (ty << 3) + i;
        const int b = r >> 11, s = r & 2047;
        #pragma unroll
        for (int g = 0; g < 2; ++g) {
            #pragma unroll
            for (int j = 0; j < 4; ++j) {
                const int c = bx * 128 + (g << 6) + (tx << 2) + j;
                const float a = acc[i][(g << 2) + j];
                if (c < 2048) {
                    const int sec = c >> 10;
                    const int cc  = c & 1023;
                    const int h = cc >> 6, d2 = cc & 63;
                    const float val = (a + bc[sec * 2048 + h * 128 + d2]) * fq[s * 64 + d2];
                    if (sec == 0) {
                        qws[((size_t)(b * 16 + h) * 2048 + s) * 64 + d2] = 2.0f * val;
                    } else {
                        const size_t o = ((size_t)(b * 16 + h) * 2048 + s) * 128 + d2;
                        kout[o] = val; kout[o + 64] = val;
                    }
                } else {
                    const int cc = c - 2048;
                    const int h = cc >> 7, d = cc & 127;
                    vout[((size_t)(b * 16 + h) * 2048 + s) * 128 + d] = a + bc[4096 + cc];
                }
            }
        }
    }
}

// ---------------------------------------------------------------------------
// Kernel 2: register-tiled flash attention (unchanged from R5, ~600 us).
// ---------------------------------------------------------------------------
__global__ __launch_bounds__(256, 2) void attn_kernel(
    const float* __restrict__ qws, const float* __restrict__ kbuf,
    const float* __restrict__ vbuf, float* __restrict__ y)
{
    __shared__ __align__(16) float  Qt[64][128];
    __shared__ __align__(16) float  Kt[64][64];
    __shared__ __align__(16) __half Vs[64][128];
    __shared__ __align__(16) __half Ps[64][128];

    const int t   = threadIdx.x;
    const int bid = blockIdx.x;
    const int bh  = bid & 31;
    const int qb  = bid >> 5;
    const int tr  = t >> 4;
    const int tc  = t & 15;
    const int s0  = qb << 7;

    const float* qp = qws  + (size_t)bh * (2048 * 64);
    const float* kb = kbuf + (size_t)bh * (2048 * 128);
    const float* vb = vbuf + (size_t)bh * (2048 * 128);

    const int kk0 = t >> 2, sg = t & 3;
    const int fi = t & 31, r0 = t >> 5;

    {
        const int qr = t & 127;
        const int dh = (t >> 7) << 5;
        const float* src = qp + (size_t)(s0 + qr) * 64 + dh;
        #pragma unroll
        for (int i = 0; i < 8; ++i) {
            float4 v4 = *(const float4*)(src + (i << 2));
            Qt[dh + (i << 2) + 0][qr] = v4.x;
            Qt[dh + (i << 2) + 1][qr] = v4.y;
            Qt[dh + (i << 2) + 2][qr] = v4.z;
            Qt[dh + (i << 2) + 3][qr] = v4.w;
        }
    }
    {
        #pragma unroll
        for (int i = 0; i < 4; ++i) {
            float4 k4 = *(const float4*)(kb + (size_t)kk0 * 128 + sg * 16 + (i << 2));
            Kt[sg * 16 + (i << 2) + 0][kk0] = k4.x;
            Kt[sg * 16 + (i << 2) + 1][kk0] = k4.y;
            Kt[sg * 16 + (i << 2) + 2][kk0] = k4.z;
            Kt[sg * 16 + (i << 2) + 3][kk0] = k4.w;
        }
        #pragma unroll
        for (int l = 0; l < 8; ++l) {
            const int key = r0 + (l << 3);
            float4 v4 = *(const float4*)(vb + (size_t)key * 128 + (fi << 2));
            __half2 h0 = __floats2half2_rn(v4.x, v4.y);
            __half2 h1 = __floats2half2_rn(v4.z, v4.w);
            float2 w; ((__half2*)&w)[0] = h0; ((__half2*)&w)[1] = h1;
            *(float2*)(&Vs[key][fi << 2]) = w;
        }
    }
    __syncthreads();

    float accO[8][8];
    #pragma unroll
    for (int i = 0; i < 8; ++i)
        #pragma unroll
        for (int j = 0; j < 8; ++j) accO[i][j] = 0.f;
    float mrow[8], lrow[8];
    #pragma unroll
    for (int i = 0; i < 8; ++i) { mrow[i] = -INFINITY; lrow[i] = 0.f; }

    const float scale = 0.08838834764831845f;  // 1/sqrt(128)

    for (int kt = 0; kt < 32; ++kt) {
        float4 kreg[4], vreg[8];
        if (kt < 31) {
            const size_t base = (size_t)(kt + 1) * 64 * 128;
            #pragma unroll
            for (int i = 0; i < 4; ++i)
                kreg[i] = *(const float4*)(kb + base + (size_t)kk0 * 128 + sg * 16 + (i << 2));
            #pragma unroll
            for (int l = 0; l < 8; ++l) {
                const int key = r0 + (l << 3);
                vreg[l] = *(const float4*)(vb + base + (size_t)key * 128 + (fi << 2));
            }
        }

        float sv[8][4];
        #pragma unroll
        for (int i = 0; i < 8; ++i)
            #pragma unroll
            for (int j = 0; j < 4; ++j) sv[i][j] = 0.f;

        #pragma unroll 4
        for (int d = 0; d < 64; ++d) {
            float4 a0 = *(const float4*)(&Qt[d][tr << 3]);
            float4 a1 = *(const float4*)(&Qt[d][(tr << 3) + 4]);
            float4 kv = *(const float4*)(&Kt[d][tc << 2]);
            const float av[8] = {a0.x, a0.y, a0.z, a0.w, a1.x, a1.y, a1.z, a1.w};
            const float bv[4] = {kv.x, kv.y, kv.z, kv.w};
            #pragma unroll
            for (int i = 0; i < 8; ++i)
                #pragma unroll
                for (int j = 0; j < 4; ++j)
                    sv[i][j] = fmaf(av[i], bv[j], sv[i][j]);
        }

        #pragma unroll
        for (int i = 0; i < 8; ++i) {
            #pragma unroll
            for (int j = 0; j < 4; ++j) sv[i][j] *= scale;
            float mx = fmaxf(fmaxf(sv[i][0], sv[i][1]), fmaxf(sv[i][2], sv[i][3]));
            mx = fmaxf(mx, __shfl_xor(mx, 1));
            mx = fmaxf(mx, __shfl_xor(mx, 2));
            mx = fmaxf(mx, __shfl_xor(mx, 4));
            mx = fmaxf(mx, __shfl_xor(mx, 8));
            const float mn = fmaxf(mrow[i], mx);
            const float al = __expf(mrow[i] - mn);
            mrow[i] = mn;
            float ps = 0.f;
            #pragma unroll
            for (int j = 0; j < 4; ++j) {
                const float p = __expf(sv[i][j] - mn);
                sv[i][j] = p;
                ps += p;
            }
            ps += __shfl_xor(ps, 1);
            ps += __shfl_xor(ps, 2);
            ps += __shfl_xor(ps, 4);
            ps += __shfl_xor(ps, 8);
            lrow[i] = lrow[i] * al + ps;
            #pragma unroll
            for (int j = 0; j < 8; ++j) accO[i][j] *= al;
        }

        #pragma unroll
        for (int j = 0; j < 4; ++j) {
            __half2 h[4];
            #pragma unroll
            for (int q = 0; q < 4; ++q) {
                __half2 hh;
                hh.x = __float2half_rn(sv[2 * q][j]);
                hh.y = __float2half_rn(sv[2 * q + 1][j]);
                h[q] = hh;
            }
            *(float4*)(&Ps[(tc << 2) + j][tr << 3]) = *(float4*)h;
        }
        __syncthreads();

        for (int key = 0; key < 64; ++key) {
            float4 praw = *(const float4*)(&Ps[key][tr << 3]);
            const __half2* ph = (const __half2*)&praw;
            float pv[8];
            #pragma unroll
            for (int q = 0; q < 4; ++q) {
                pv[2 * q]     = __low2float(ph[q]);
                pv[2 * q + 1] = __high2float(ph[q]);
            }
            float2 vr0 = *(const float2*)(&Vs[key][tc << 2]);
            float2 vr1 = *(const float2*)(&Vs[key][64 + (tc << 2)]);
            const __half2* vh0 = (const __half2*)&vr0;
            const __half2* vh1 = (const __half2*)&vr1;
            const float vv[8] = {
                __low2float(vh0[0]), __high2float(vh0[0]),
                __low2float(vh0[1]), __high2float(vh0[1]),
                __low2float(vh1[0]), __high2float(vh1[0]),
                __low2float(vh1[1]), __high2float(vh1[1])};
            #pragma unroll
            for (int i = 0; i < 8; ++i)
                #pragma unroll
                for (int j = 0; j < 8; ++j)
                    accO[i][j] = fmaf(pv[i], vv[j], accO[i][j]);
        }

        if (kt < 31) {
            __syncthreads();
            #pragma unroll
            for (int i = 0; i < 4; ++i) {
                Kt[sg * 16 + (i << 2) + 0][kk0] = kreg[i].x;
                Kt[sg * 16 + (i << 2) + 1][kk0] = kreg[i].y;
                Kt[sg * 16 + (i << 2) + 2][kk0] = kreg[i].z;
                Kt[sg * 16 + (i << 2) + 3][kk0] = kreg[i].w;
            }
            #pragma unroll
            for (int l = 0; l < 8; ++l) {
                const int key = r0 + (l << 3);
                __half2 h0 = __floats2half2_rn(vreg[l].x, vreg[l].y);
                __half2 h1 = __floats2half2_rn(vreg[l].z, vreg[l].w);
                float2 w; ((__half2*)&w)[0] = h0; ((__half2*)&w)[1] = h1;
                *(float2*)(&Vs[key][fi << 2]) = w;
            }
            __syncthreads();
        }
    }

    const int b = bh >> 4, h = bh & 15;
    #pragma unroll
    for (int i = 0; i < 8; ++i) {
        const float inv = 1.f / lrow[i];
        const int srow = s0 + (tr << 3) + i;
        float* yp = y + ((size_t)(b * 2048 + srow)) * 2048 + h * 128;
        float4 o0, o1;
        o0.x = accO[i][0] * inv; o0.y = accO[i][1] * inv;
        o0.z = accO[i][2] * inv; o0.w = accO[i][3] * inv;
        o1.x = accO[i][4] * inv; o1.y = accO[i][5] * inv;
        o1.z = accO[i][6] * inv; o1.w = accO[i][7] * inv;
        *(float4*)(yp + (tc << 2))      = o0;
        *(float4*)(yp + 64 + (tc << 2)) = o1;
    }
}

extern "C" void kernel_launch(void* const* d_in, const int* in_sizes, int n_in,
                              void* d_out, int out_size, void* d_ws, size_t ws_size,
                              hipStream_t stream)
{
    const float* x  = (const float*)d_in[0];
    const float* Wc = (const float*)d_in[1];
    const float* bc = (const float*)d_in[2];
    const float* fq = (const float*)d_in[3];
    float* out = (float*)d_out;
    float* qws = (float*)d_ws;   // compact q, (B,H,S,64) fp32 = 16 MiB

    dim3 g1(32, 32);
    gemm_rope_kernel<<<g1, 256, 0, stream>>>(x, Wc, bc, fq, qws, out);
    attn_kernel<<<512, 256, 0, stream>>>(qws, out + K_OFF, out + V_OFF, out + Y_OFF);
}

// Round 7
// 1886.776 us; speedup vs baseline: 7.3807x; 7.3807x over previous
//
#include <hip/hip_runtime.h>
#include <hip/hip_fp16.h>
#include <math.h>

// Problem constants
#define KDIM  2048
// d_out layout (floats): y | k | v
#define Y_OFF 0
#define K_OFF 8388608
#define V_OFF 16777216

// ---------------------------------------------------------------------------
// Kernel 1: qkv = x @ Wc^T + bc, fused with rope-scale + scatter.
// 8x8 per-thread tile, BM=BN=128, BK=16, double-buffered LDS (1 barrier/tile).
// NOTE: no min-occupancy hint — __launch_bounds__(256,4) clamped VGPRs to 64
// and spilled acc[8][8] to scratch (R6: 50 GB/dispatch scratch traffic).
// ---------------------------------------------------------------------------
__global__ __launch_bounds__(256) void gemm_rope_kernel(
    const float* __restrict__ x, const float* __restrict__ Wc,
    const float* __restrict__ bc, const float* __restrict__ fq,
    float* __restrict__ qws, float* __restrict__ out)
{
    // k-major, pad 132 (132 mod 32 == 4): staging writes 2-way (free),
    // frag reads broadcast/2-way (free).
    __shared__ __align__(16) float As[2][16][132];
    __shared__ __align__(16) float Bs[2][16][132];

    const int t  = threadIdx.x;
    const int bx = blockIdx.x;   // col tile 0..31 (reduced cols)
    const int by = blockIdx.y;   // row tile 0..31
    const int tx = t & 15, ty = t >> 4;

    // staging mapping: thread -> (row srow_, row+64), k-chunk skc
    const int srow_ = t >> 2;        // 0..63
    const int skc   = (t & 3) << 2;  // 0,4,8,12

    // B source rows (fixed per thread)
    int bsrc[2];
    #pragma unroll
    for (int p = 0; p < 2; ++p) {
        const int c = bx * 128 + srow_ + (p << 6);
        int sr;
        if (c < 1024)      sr = ((c >> 6) << 7) + (c & 63);
        else if (c < 2048) sr = 2048 + (((c - 1024) >> 6) << 7) + (c & 63);
        else               sr = 4096 + (c - 2048);
        bsrc[p] = sr;
    }
    const int arow0 = by * 128 + srow_;

    float acc[8][8];
    #pragma unroll
    for (int i = 0; i < 8; ++i)
        #pragma unroll
        for (int j = 0; j < 8; ++j) acc[i][j] = 0.f;

    // ---- stage tile 0 into buffer 0
    #pragma unroll
    for (int p = 0; p < 2; ++p) {
        float4 va = *(const float4*)(x + (size_t)(arow0 + (p << 6)) * KDIM + skc);
        As[0][skc + 0][srow_ + (p << 6)] = va.x;
        As[0][skc + 1][srow_ + (p << 6)] = va.y;
        As[0][skc + 2][srow_ + (p << 6)] = va.z;
        As[0][skc + 3][srow_ + (p << 6)] = va.w;
        float4 vb = *(const float4*)(Wc + (size_t)bsrc[p] * KDIM + skc);
        Bs[0][skc + 0][srow_ + (p << 6)] = vb.x;
        Bs[0][skc + 1][srow_ + (p << 6)] = vb.y;
        Bs[0][skc + 2][srow_ + (p << 6)] = vb.z;
        Bs[0][skc + 3][srow_ + (p << 6)] = vb.w;
    }
    __syncthreads();

    for (int kt = 0; kt < 128; ++kt) {
        const int cur = kt & 1;

        // ---- prefetch next K-tile into registers (latency hides under FMA)
        float4 pa[2], pb[2];
        if (kt < 127) {
            const int kn = (kt + 1) << 4;
            #pragma unroll
            for (int p = 0; p < 2; ++p) {
                pa[p] = *(const float4*)(x  + (size_t)(arow0 + (p << 6)) * KDIM + kn + skc);
                pb[p] = *(const float4*)(Wc + (size_t)bsrc[p] * KDIM + kn + skc);
            }
        }

        // ---- compute 16 kk on current buffer
        #pragma unroll
        for (int kk = 0; kk < 16; ++kk) {
            float4 a0 = *(const float4*)(&As[cur][kk][ty << 3]);
            float4 a1 = *(const float4*)(&As[cur][kk][(ty << 3) + 4]);
            float4 b0 = *(const float4*)(&Bs[cur][kk][tx << 2]);
            float4 b1 = *(const float4*)(&Bs[cur][kk][64 + (tx << 2)]);
            const float av[8] = {a0.x, a0.y, a0.z, a0.w, a1.x, a1.y, a1.z, a1.w};
            const float bv[8] = {b0.x, b0.y, b0.z, b0.w, b1.x, b1.y, b1.z, b1.w};
            #pragma unroll
            for (int i = 0; i < 8; ++i)
                #pragma unroll
                for (int j = 0; j < 8; ++j)
                    acc[i][j] = fmaf(av[i], bv[j], acc[i][j]);
        }

        // ---- commit prefetch to the other buffer; one barrier per tile
        if (kt < 127) {
            const int nxt = cur ^ 1;
            #pragma unroll
            for (int p = 0; p < 2; ++p) {
                const int r = srow_ + (p << 6);
                As[nxt][skc + 0][r] = pa[p].x;
                As[nxt][skc + 1][r] = pa[p].y;
                As[nxt][skc + 2][r] = pa[p].z;
                As[nxt][skc + 3][r] = pa[p].w;
                Bs[nxt][skc + 0][r] = pb[p].x;
                Bs[nxt][skc + 1][r] = pb[p].y;
                Bs[nxt][skc + 2][r] = pb[p].w == pb[p].w ? pb[p].z : pb[p].z; // keep simple
                Bs[nxt][skc + 2][r] = pb[p].z;
                Bs[nxt][skc + 3][r] = pb[p].w;
            }
            __syncthreads();
        }
    }

    // ---- epilogue: bias + rope-scale + scatter
    float* kout = out + K_OFF;
    float* vout = out + V_OFF;
    #pragma unroll
    for (int i = 0; i < 8; ++i) {
        const int r = by * 128 + (ty << 3) + i;
        const int b = r >> 11, s = r & 2047;
        #pragma unroll
        for (int g = 0; g < 2; ++g) {
            #pragma unroll
            for (int j = 0; j < 4; ++j) {
                const int c = bx * 128 + (g << 6) + (tx << 2) + j;
                const float a = acc[i][(g << 2) + j];
                if (c < 2048) {
                    const int sec = c >> 10;
                    const int cc  = c & 1023;
                    const int h = cc >> 6, d2 = cc & 63;
                    const float val = (a + bc[sec * 2048 + h * 128 + d2]) * fq[s * 64 + d2];
                    if (sec == 0) {
                        qws[((size_t)(b * 16 + h) * 2048 + s) * 64 + d2] = 2.0f * val;
                    } else {
                        const size_t o = ((size_t)(b * 16 + h) * 2048 + s) * 128 + d2;
                        kout[o] = val; kout[o + 64] = val;
                    }
                } else {
                    const int cc = c - 2048;
                    const int h = cc >> 7, d = cc & 127;
                    vout[((size_t)(b * 16 + h) * 2048 + s) * 128 + d] = a + bc[4096 + cc];
                }
            }
        }
    }
}

// ---------------------------------------------------------------------------
// Kernel 2: register-tiled flash attention (unchanged from R5, ~600 us).
// ---------------------------------------------------------------------------
__global__ __launch_bounds__(256, 2) void attn_kernel(
    const float* __restrict__ qws, const float* __restrict__ kbuf,
    const float* __restrict__ vbuf, float* __restrict__ y)
{
    __shared__ __align__(16) float  Qt[64][128];
    __shared__ __align__(16) float  Kt[64][64];
    __shared__ __align__(16) __half Vs[64][128];
    __shared__ __align__(16) __half Ps[64][128];

    const int t   = threadIdx.x;
    const int bid = blockIdx.x;
    const int bh  = bid & 31;
    const int qb  = bid >> 5;
    const int tr  = t >> 4;
    const int tc  = t & 15;
    const int s0  = qb << 7;

    const float* qp = qws  + (size_t)bh * (2048 * 64);
    const float* kb = kbuf + (size_t)bh * (2048 * 128);
    const float* vb = vbuf + (size_t)bh * (2048 * 128);

    const int kk0 = t >> 2, sg = t & 3;
    const int fi = t & 31, r0 = t >> 5;

    {
        const int qr = t & 127;
        const int dh = (t >> 7) << 5;
        const float* src = qp + (size_t)(s0 + qr) * 64 + dh;
        #pragma unroll
        for (int i = 0; i < 8; ++i) {
            float4 v4 = *(const float4*)(src + (i << 2));
            Qt[dh + (i << 2) + 0][qr] = v4.x;
            Qt[dh + (i << 2) + 1][qr] = v4.y;
            Qt[dh + (i << 2) + 2][qr] = v4.z;
            Qt[dh + (i << 2) + 3][qr] = v4.w;
        }
    }
    {
        #pragma unroll
        for (int i = 0; i < 4; ++i) {
            float4 k4 = *(const float4*)(kb + (size_t)kk0 * 128 + sg * 16 + (i << 2));
            Kt[sg * 16 + (i << 2) + 0][kk0] = k4.x;
            Kt[sg * 16 + (i << 2) + 1][kk0] = k4.y;
            Kt[sg * 16 + (i << 2) + 2][kk0] = k4.z;
            Kt[sg * 16 + (i << 2) + 3][kk0] = k4.w;
        }
        #pragma unroll
        for (int l = 0; l < 8; ++l) {
            const int key = r0 + (l << 3);
            float4 v4 = *(const float4*)(vb + (size_t)key * 128 + (fi << 2));
            __half2 h0 = __floats2half2_rn(v4.x, v4.y);
            __half2 h1 = __floats2half2_rn(v4.z, v4.w);
            float2 w; ((__half2*)&w)[0] = h0; ((__half2*)&w)[1] = h1;
            *(float2*)(&Vs[key][fi << 2]) = w;
        }
    }
    __syncthreads();

    float accO[8][8];
    #pragma unroll
    for (int i = 0; i < 8; ++i)
        #pragma unroll
        for (int j = 0; j < 8; ++j) accO[i][j] = 0.f;
    float mrow[8], lrow[8];
    #pragma unroll
    for (int i = 0; i < 8; ++i) { mrow[i] = -INFINITY; lrow[i] = 0.f; }

    const float scale = 0.08838834764831845f;  // 1/sqrt(128)

    for (int kt = 0; kt < 32; ++kt) {
        float4 kreg[4], vreg[8];
        if (kt < 31) {
            const size_t base = (size_t)(kt + 1) * 64 * 128;
            #pragma unroll
            for (int i = 0; i < 4; ++i)
                kreg[i] = *(const float4*)(kb + base + (size_t)kk0 * 128 + sg * 16 + (i << 2));
            #pragma unroll
            for (int l = 0; l < 8; ++l) {
                const int key = r0 + (l << 3);
                vreg[l] = *(const float4*)(vb + base + (size_t)key * 128 + (fi << 2));
            }
        }

        float sv[8][4];
        #pragma unroll
        for (int i = 0; i < 8; ++i)
            #pragma unroll
            for (int j = 0; j < 4; ++j) sv[i][j] = 0.f;

        #pragma unroll 4
        for (int d = 0; d < 64; ++d) {
            float4 a0 = *(const float4*)(&Qt[d][tr << 3]);
            float4 a1 = *(const float4*)(&Qt[d][(tr << 3) + 4]);
            float4 kv = *(const float4*)(&Kt[d][tc << 2]);
            const float av[8] = {a0.x, a0.y, a0.z, a0.w, a1.x, a1.y, a1.z, a1.w};
            const float bv[4] = {kv.x, kv.y, kv.z, kv.w};
            #pragma unroll
            for (int i = 0; i < 8; ++i)
                #pragma unroll
                for (int j = 0; j < 4; ++j)
                    sv[i][j] = fmaf(av[i], bv[j], sv[i][j]);
        }

        #pragma unroll
        for (int i = 0; i < 8; ++i) {
            #pragma unroll
            for (int j = 0; j < 4; ++j) sv[i][j] *= scale;
            float mx = fmaxf(fmaxf(sv[i][0], sv[i][1]), fmaxf(sv[i][2], sv[i][3]));
            mx = fmaxf(mx, __shfl_xor(mx, 1));
            mx = fmaxf(mx, __shfl_xor(mx, 2));
            mx = fmaxf(mx, __shfl_xor(mx, 4));
            mx = fmaxf(mx, __shfl_xor(mx, 8));
            const float mn = fmaxf(mrow[i], mx);
            const float al = __expf(mrow[i] - mn);
            mrow[i] = mn;
            float ps = 0.f;
            #pragma unroll
            for (int j = 0; j < 4; ++j) {
                const float p = __expf(sv[i][j] - mn);
                sv[i][j] = p;
                ps += p;
            }
            ps += __shfl_xor(ps, 1);
            ps += __shfl_xor(ps, 2);
            ps += __shfl_xor(ps, 4);
            ps += __shfl_xor(ps, 8);
            lrow[i] = lrow[i] * al + ps;
            #pragma unroll
            for (int j = 0; j < 8; ++j) accO[i][j] *= al;
        }

        #pragma unroll
        for (int j = 0; j < 4; ++j) {
            __half2 h[4];
            #pragma unroll
            for (int q = 0; q < 4; ++q) {
                __half2 hh;
                hh.x = __float2half_rn(sv[2 * q][j]);
                hh.y = __float2half_rn(sv[2 * q + 1][j]);
                h[q] = hh;
            }
            *(float4*)(&Ps[(tc << 2) + j][tr << 3]) = *(float4*)h;
        }
        __syncthreads();

        for (int key = 0; key < 64; ++key) {
            float4 praw = *(const float4*)(&Ps[key][tr << 3]);
            const __half2* ph = (const __half2*)&praw;
            float pv[8];
            #pragma unroll
            for (int q = 0; q < 4; ++q) {
                pv[2 * q]     = __low2float(ph[q]);
                pv[2 * q + 1] = __high2float(ph[q]);
            }
            float2 vr0 = *(const float2*)(&Vs[key][tc << 2]);
            float2 vr1 = *(const float2*)(&Vs[key][64 + (tc << 2)]);
            const __half2* vh0 = (const __half2*)&vr0;
            const __half2* vh1 = (const __half2*)&vr1;
            const float vv[8] = {
                __low2float(vh0[0]), __high2float(vh0[0]),
                __low2float(vh0[1]), __high2float(vh0[1]),
                __low2float(vh1[0]), __high2float(vh1[0]),
                __low2float(vh1[1]), __high2float(vh1[1])};
            #pragma unroll
            for (int i = 0; i < 8; ++i)
                #pragma unroll
                for (int j = 0; j < 8; ++j)
                    accO[i][j] = fmaf(pv[i], vv[j], accO[i][j]);
        }

        if (kt < 31) {
            __syncthreads();
            #pragma unroll
            for (int i = 0; i < 4; ++i) {
                Kt[sg * 16 + (i << 2) + 0][kk0] = kreg[i].x;
                Kt[sg * 16 + (i << 2) + 1][kk0] = kreg[i].y;
                Kt[sg * 16 + (i << 2) + 2][kk0] = kreg[i].z;
                Kt[sg * 16 + (i << 2) + 3][kk0] = kreg[i].w;
            }
            #pragma unroll
            for (int l = 0; l < 8; ++l) {
                const int key = r0 + (l << 3);
                __half2 h0 = __floats2half2_rn(vreg[l].x, vreg[l].y);
                __half2 h1 = __floats2half2_rn(vreg[l].z, vreg[l].w);
                float2 w; ((__half2*)&w)[0] = h0; ((__half2*)&w)[1] = h1;
                *(float2*)(&Vs[key][fi << 2]) = w;
            }
            __syncthreads();
        }
    }

    const int b = bh >> 4, h = bh & 15;
    #pragma unroll
    for (int i = 0; i < 8; ++i) {
        const float inv = 1.f / lrow[i];
        const int srow = s0 + (tr << 3) + i;
        float* yp = y + ((size_t)(b * 2048 + srow)) * 2048 + h * 128;
        float4 o0, o1;
        o0.x = accO[i][0] * inv; o0.y = accO[i][1] * inv;
        o0.z = accO[i][2] * inv; o0.w = accO[i][3] * inv;
        o1.x = accO[i][4] * inv; o1.y = accO[i][5] * inv;
        o1.z = accO[i][6] * inv; o1.w = accO[i][7] * inv;
        *(float4*)(yp + (tc << 2))      = o0;
        *(float4*)(yp + 64 + (tc << 2)) = o1;
    }
}

extern "C" void kernel_launch(void* const* d_in, const int* in_sizes, int n_in,
                              void* d_out, int out_size, void* d_ws, size_t ws_size,
                              hipStream_t stream)
{
    const float* x  = (const float*)d_in[0];
    const float* Wc = (const float*)d_in[1];
    const float* bc = (const float*)d_in[2];
    const float* fq = (const float*)d_in[3];
    float* out = (float*)d_out;
    float* qws = (float*)d_ws;   // compact q, (B,H,S,64) fp32 = 16 MiB

    dim3 g1(32, 32);
    gemm_rope_kernel<<<g1, 256, 0, stream>>>(x, Wc, bc, fq, qws, out);
    attn_kernel<<<512, 256, 0, stream>>>(qws, out + K_OFF, out + V_OFF, out + Y_OFF);
}

// Round 8
// 1563.318 us; speedup vs baseline: 8.9078x; 1.2069x over previous
//
#include <hip/hip_runtime.h>
#include <hip/hip_fp16.h>
#include <math.h>

// Problem constants
#define KDIM  2048
// d_out layout (floats): y | k | v
#define Y_OFF 0
#define K_OFF 8388608
#define V_OFF 16777216

// ---------------------------------------------------------------------------
// Kernel 1: qkv = x @ Wc^T + bc, fused with rope-scale + scatter.
// 8x8 per-thread tile, BM=BN=128, BK=16, SINGLE-buffer LDS, 2 barriers/tile.
// No launch-bounds min-occupancy (R6: (256,4) clamped VGPR->64, spilled acc).
// No explicit prefetch regs (R7: 180 VGPR -> 1 block/CU). Compiler may hoist
// the global loads across the barrier for free pipelining.
// ---------------------------------------------------------------------------
__global__ __launch_bounds__(256) void gemm_rope_kernel(
    const float* __restrict__ x, const float* __restrict__ Wc,
    const float* __restrict__ bc, const float* __restrict__ fq,
    float* __restrict__ qws, float* __restrict__ out)
{
    // k-major, pad 132 (132 mod 32 == 4): staging writes 2-way (free),
    // frag reads broadcast/2-way (free).
    __shared__ __align__(16) float As[16][132];
    __shared__ __align__(16) float Bs[16][132];

    const int t  = threadIdx.x;
    const int bx = blockIdx.x;   // col tile 0..31 (reduced cols)
    const int by = blockIdx.y;   // row tile 0..31
    const int tx = t & 15, ty = t >> 4;

    // staging mapping: thread -> rows (srow_, srow_+64), k-chunk skc
    const int srow_ = t >> 2;        // 0..63
    const int skc   = (t & 3) << 2;  // 0,4,8,12

    // B source rows (fixed per thread)
    int bsrc[2];
    #pragma unroll
    for (int p = 0; p < 2; ++p) {
        const int c = bx * 128 + srow_ + (p << 6);
        int sr;
        if (c < 1024)      sr = ((c >> 6) << 7) + (c & 63);
        else if (c < 2048) sr = 2048 + (((c - 1024) >> 6) << 7) + (c & 63);
        else               sr = 4096 + (c - 2048);
        bsrc[p] = sr;
    }
    const int arow0 = by * 128 + srow_;

    float acc[8][8];
    #pragma unroll
    for (int i = 0; i < 8; ++i)
        #pragma unroll
        for (int j = 0; j < 8; ++j) acc[i][j] = 0.f;

    for (int kt = 0; kt < 128; ++kt) {
        const int k0 = kt << 4;

        // ---- stage tile kt (global -> LDS, k-major transpose)
        float4 va0 = *(const float4*)(x + (size_t)arow0 * KDIM + k0 + skc);
        float4 va1 = *(const float4*)(x + (size_t)(arow0 + 64) * KDIM + k0 + skc);
        float4 vb0 = *(const float4*)(Wc + (size_t)bsrc[0] * KDIM + k0 + skc);
        float4 vb1 = *(const float4*)(Wc + (size_t)bsrc[1] * KDIM + k0 + skc);

        As[skc + 0][srow_] = va0.x; As[skc + 1][srow_] = va0.y;
        As[skc + 2][srow_] = va0.z; As[skc + 3][srow_] = va0.w;
        As[skc + 0][srow_ + 64] = va1.x; As[skc + 1][srow_ + 64] = va1.y;
        As[skc + 2][srow_ + 64] = va1.z; As[skc + 3][srow_ + 64] = va1.w;
        Bs[skc + 0][srow_] = vb0.x; Bs[skc + 1][srow_] = vb0.y;
        Bs[skc + 2][srow_] = vb0.z; Bs[skc + 3][srow_] = vb0.w;
        Bs[skc + 0][srow_ + 64] = vb1.x; Bs[skc + 1][srow_ + 64] = vb1.y;
        Bs[skc + 2][srow_ + 64] = vb1.z; Bs[skc + 3][srow_ + 64] = vb1.w;
        __syncthreads();

        // ---- compute 16 kk on the buffer
        #pragma unroll
        for (int kk = 0; kk < 16; ++kk) {
            float4 a0 = *(const float4*)(&As[kk][ty << 3]);
            float4 a1 = *(const float4*)(&As[kk][(ty << 3) + 4]);
            float4 b0 = *(const float4*)(&Bs[kk][tx << 2]);
            float4 b1 = *(const float4*)(&Bs[kk][64 + (tx << 2)]);
            const float av[8] = {a0.x, a0.y, a0.z, a0.w, a1.x, a1.y, a1.z, a1.w};
            const float bv[8] = {b0.x, b0.y, b0.z, b0.w, b1.x, b1.y, b1.z, b1.w};
            #pragma unroll
            for (int i = 0; i < 8; ++i)
                #pragma unroll
                for (int j = 0; j < 8; ++j)
                    acc[i][j] = fmaf(av[i], bv[j], acc[i][j]);
        }
        __syncthreads();
    }

    // ---- epilogue: bias + rope-scale + scatter
    float* kout = out + K_OFF;
    float* vout = out + V_OFF;
    #pragma unroll
    for (int i = 0; i < 8; ++i) {
        const int r = by * 128 + (ty << 3) + i;
        const int b = r >> 11, s = r & 2047;
        #pragma unroll
        for (int g = 0; g < 2; ++g) {
            #pragma unroll
            for (int j = 0; j < 4; ++j) {
                const int c = bx * 128 + (g << 6) + (tx << 2) + j;
                const float a = acc[i][(g << 2) + j];
                if (c < 2048) {
                    const int sec = c >> 10;
                    const int cc  = c & 1023;
                    const int h = cc >> 6, d2 = cc & 63;
                    const float val = (a + bc[sec * 2048 + h * 128 + d2]) * fq[s * 64 + d2];
                    if (sec == 0) {
                        qws[((size_t)(b * 16 + h) * 2048 + s) * 64 + d2] = 2.0f * val;
                    } else {
                        const size_t o = ((size_t)(b * 16 + h) * 2048 + s) * 128 + d2;
                        kout[o] = val; kout[o + 64] = val;
                    }
                } else {
                    const int cc = c - 2048;
                    const int h = cc >> 7, d = cc & 127;
                    vout[((size_t)(b * 16 + h) * 2048 + s) * 128 + d] = a + bc[4096 + cc];
                }
            }
        }
    }
}

// ---------------------------------------------------------------------------
// Kernel 2: register-tiled flash attention (unchanged from R5, ~510 us).
// ---------------------------------------------------------------------------
__global__ __launch_bounds__(256, 2) void attn_kernel(
    const float* __restrict__ qws, const float* __restrict__ kbuf,
    const float* __restrict__ vbuf, float* __restrict__ y)
{
    __shared__ __align__(16) float  Qt[64][128];
    __shared__ __align__(16) float  Kt[64][64];
    __shared__ __align__(16) __half Vs[64][128];
    __shared__ __align__(16) __half Ps[64][128];

    const int t   = threadIdx.x;
    const int bid = blockIdx.x;
    const int bh  = bid & 31;
    const int qb  = bid >> 5;
    const int tr  = t >> 4;
    const int tc  = t & 15;
    const int s0  = qb << 7;

    const float* qp = qws  + (size_t)bh * (2048 * 64);
    const float* kb = kbuf + (size_t)bh * (2048 * 128);
    const float* vb = vbuf + (size_t)bh * (2048 * 128);

    const int kk0 = t >> 2, sg = t & 3;
    const int fi = t & 31, r0 = t >> 5;

    {
        const int qr = t & 127;
        const int dh = (t >> 7) << 5;
        const float* src = qp + (size_t)(s0 + qr) * 64 + dh;
        #pragma unroll
        for (int i = 0; i < 8; ++i) {
            float4 v4 = *(const float4*)(src + (i << 2));
            Qt[dh + (i << 2) + 0][qr] = v4.x;
            Qt[dh + (i << 2) + 1][qr] = v4.y;
            Qt[dh + (i << 2) + 2][qr] = v4.z;
            Qt[dh + (i << 2) + 3][qr] = v4.w;
        }
    }
    {
        #pragma unroll
        for (int i = 0; i < 4; ++i) {
            float4 k4 = *(const float4*)(kb + (size_t)kk0 * 128 + sg * 16 + (i << 2));
            Kt[sg * 16 + (i << 2) + 0][kk0] = k4.x;
            Kt[sg * 16 + (i << 2) + 1][kk0] = k4.y;
            Kt[sg * 16 + (i << 2) + 2][kk0] = k4.z;
            Kt[sg * 16 + (i << 2) + 3][kk0] = k4.w;
        }
        #pragma unroll
        for (int l = 0; l < 8; ++l) {
            const int key = r0 + (l << 3);
            float4 v4 = *(const float4*)(vb + (size_t)key * 128 + (fi << 2));
            __half2 h0 = __floats2half2_rn(v4.x, v4.y);
            __half2 h1 = __floats2half2_rn(v4.z, v4.w);
            float2 w; ((__half2*)&w)[0] = h0; ((__half2*)&w)[1] = h1;
            *(float2*)(&Vs[key][fi << 2]) = w;
        }
    }
    __syncthreads();

    float accO[8][8];
    #pragma unroll
    for (int i = 0; i < 8; ++i)
        #pragma unroll
        for (int j = 0; j < 8; ++j) accO[i][j] = 0.f;
    float mrow[8], lrow[8];
    #pragma unroll
    for (int i = 0; i < 8; ++i) { mrow[i] = -INFINITY; lrow[i] = 0.f; }

    const float scale = 0.08838834764831845f;  // 1/sqrt(128)

    for (int kt = 0; kt < 32; ++kt) {
        float4 kreg[4], vreg[8];
        if (kt < 31) {
            const size_t base = (size_t)(kt + 1) * 64 * 128;
            #pragma unroll
            for (int i = 0; i < 4; ++i)
                kreg[i] = *(const float4*)(kb + base + (size_t)kk0 * 128 + sg * 16 + (i << 2));
            #pragma unroll
            for (int l = 0; l < 8; ++l) {
                const int key = r0 + (l << 3);
                vreg[l] = *(const float4*)(vb + base + (size_t)key * 128 + (fi << 2));
            }
        }

        float sv[8][4];
        #pragma unroll
        for (int i = 0; i < 8; ++i)
            #pragma unroll
            for (int j = 0; j < 4; ++j) sv[i][j] = 0.f;

        #pragma unroll 4
        for (int d = 0; d < 64; ++d) {
            float4 a0 = *(const float4*)(&Qt[d][tr << 3]);
            float4 a1 = *(const float4*)(&Qt[d][(tr << 3) + 4]);
            float4 kv = *(const float4*)(&Kt[d][tc << 2]);
            const float av[8] = {a0.x, a0.y, a0.z, a0.w, a1.x, a1.y, a1.z, a1.w};
            const float bv[4] = {kv.x, kv.y, kv.z, kv.w};
            #pragma unroll
            for (int i = 0; i < 8; ++i)
                #pragma unroll
                for (int j = 0; j < 4; ++j)
                    sv[i][j] = fmaf(av[i], bv[j], sv[i][j]);
        }

        #pragma unroll
        for (int i = 0; i < 8; ++i) {
            #pragma unroll
            for (int j = 0; j < 4; ++j) sv[i][j] *= scale;
            float mx = fmaxf(fmaxf(sv[i][0], sv[i][1]), fmaxf(sv[i][2], sv[i][3]));
            mx = fmaxf(mx, __shfl_xor(mx, 1));
            mx = fmaxf(mx, __shfl_xor(mx, 2));
            mx = fmaxf(mx, __shfl_xor(mx, 4));
            mx = fmaxf(mx, __shfl_xor(mx, 8));
            const float mn = fmaxf(mrow[i], mx);
            const float al = __expf(mrow[i] - mn);
            mrow[i] = mn;
            float ps = 0.f;
            #pragma unroll
            for (int j = 0; j < 4; ++j) {
                const float p = __expf(sv[i][j] - mn);
                sv[i][j] = p;
                ps += p;
            }
            ps += __shfl_xor(ps, 1);
            ps += __shfl_xor(ps, 2);
            ps += __shfl_xor(ps, 4);
            ps += __shfl_xor(ps, 8);
            lrow[i] = lrow[i] * al + ps;
            #pragma unroll
            for (int j = 0; j < 8; ++j) accO[i][j] *= al;
        }

        #pragma unroll
        for (int j = 0; j < 4; ++j) {
            __half2 h[4];
            #pragma unroll
            for (int q = 0; q < 4; ++q) {
                __half2 hh;
                hh.x = __float2half_rn(sv[2 * q][j]);
                hh.y = __float2half_rn(sv[2 * q + 1][j]);
                h[q] = hh;
            }
            *(float4*)(&Ps[(tc << 2) + j][tr << 3]) = *(float4*)h;
        }
        __syncthreads();

        for (int key = 0; key < 64; ++key) {
            float4 praw = *(const float4*)(&Ps[key][tr << 3]);
            const __half2* ph = (const __half2*)&praw;
            float pv[8];
            #pragma unroll
            for (int q = 0; q < 4; ++q) {
                pv[2 * q]     = __low2float(ph[q]);
                pv[2 * q + 1] = __high2float(ph[q]);
            }
            float2 vr0 = *(const float2*)(&Vs[key][tc << 2]);
            float2 vr1 = *(const float2*)(&Vs[key][64 + (tc << 2)]);
            const __half2* vh0 = (const __half2*)&vr0;
            const __half2* vh1 = (const __half2*)&vr1;
            const float vv[8] = {
                __low2float(vh0[0]), __high2float(vh0[0]),
                __low2float(vh0[1]), __high2float(vh0[1]),
                __low2float(vh1[0]), __high2float(vh1[0]),
                __low2float(vh1[1]), __high2float(vh1[1])};
            #pragma unroll
            for (int i = 0; i < 8; ++i)
                #pragma unroll
                for (int j = 0; j < 8; ++j)
                    accO[i][j] = fmaf(pv[i], vv[j], accO[i][j]);
        }

        if (kt < 31) {
            __syncthreads();
            #pragma unroll
            for (int i = 0; i < 4; ++i) {
                Kt[sg * 16 + (i << 2) + 0][kk0] = kreg[i].x;
                Kt[sg * 16 + (i << 2) + 1][kk0] = kreg[i].y;
                Kt[sg * 16 + (i << 2) + 2][kk0] = kreg[i].z;
                Kt[sg * 16 + (i << 2) + 3][kk0] = kreg[i].w;
            }
            #pragma unroll
            for (int l = 0; l < 8; ++l) {
                const int key = r0 + (l << 3);
                __half2 h0 = __floats2half2_rn(vreg[l].x, vreg[l].y);
                __half2 h1 = __floats2half2_rn(vreg[l].z, vreg[l].w);
                float2 w; ((__half2*)&w)[0] = h0; ((__half2*)&w)[1] = h1;
                *(float2*)(&Vs[key][fi << 2]) = w;
            }
            __syncthreads();
        }
    }

    const int b = bh >> 4, h = bh & 15;
    #pragma unroll
    for (int i = 0; i < 8; ++i) {
        const float inv = 1.f / lrow[i];
        const int srow = s0 + (tr << 3) + i;
        float* yp = y + ((size_t)(b * 2048 + srow)) * 2048 + h * 128;
        float4 o0, o1;
        o0.x = accO[i][0] * inv; o0.y = accO[i][1] * inv;
        o0.z = accO[i][2] * inv; o0.w = accO[i][3] * inv;
        o1.x = accO[i][4] * inv; o1.y = accO[i][5] * inv;
        o1.z = accO[i][6] * inv; o1.w = accO[i][7] * inv;
        *(float4*)(yp + (tc << 2))      = o0;
        *(float4*)(yp + 64 + (tc << 2)) = o1;
    }
}

extern "C" void kernel_launch(void* const* d_in, const int* in_sizes, int n_in,
                              void* d_out, int out_size, void* d_ws, size_t ws_size,
                              hipStream_t stream)
{
    const float* x  = (const float*)d_in[0];
    const float* Wc = (const float*)d_in[1];
    const float* bc = (const float*)d_in[2];
    const float* fq = (const float*)d_in[3];
    float* out = (float*)d_out;
    float* qws = (float*)d_ws;   // compact q, (B,H,S,64) fp32 = 16 MiB

    dim3 g1(32, 32);
    gemm_rope_kernel<<<g1, 256, 0, stream>>>(x, Wc, bc, fq, qws, out);
    attn_kernel<<<512, 256, 0, stream>>>(qws, out + K_OFF, out + V_OFF, out + Y_OFF);
}

// Round 9
// 1543.213 us; speedup vs baseline: 9.0238x; 1.0130x over previous
//
#include <hip/hip_runtime.h>
#include <hip/hip_fp16.h>
#include <math.h>

// Problem constants
#define KDIM  2048
// d_out layout (floats): y | k | v
#define Y_OFF 0
#define K_OFF 8388608
#define V_OFF 16777216

// ---------------------------------------------------------------------------
// Kernel 1: qkv = x @ Wc^T + bc, fused with rope-scale + scatter.
// 8x8 per-thread tile, BM=BN=128, BK=32, single-buffer LDS, 2 barriers/tile
// (64 tiles -> half the barriers of R8). Staging: 2 lanes per row, write
// banks (4kc+row)%32 conflict-free. No launch-bounds min-occupancy (R6
// lesson), no reg-prefetch (R7 lesson).
// ---------------------------------------------------------------------------
__global__ __launch_bounds__(256) void gemm_rope_kernel(
    const float* __restrict__ x, const float* __restrict__ Wc,
    const float* __restrict__ bc, const float* __restrict__ fq,
    float* __restrict__ qws, float* __restrict__ out)
{
    __shared__ __align__(16) float As[32][132];   // k-major, pad 132
    __shared__ __align__(16) float Bs[32][132];

    const int t  = threadIdx.x;
    const int bx = blockIdx.x;   // col tile 0..31 (reduced cols)
    const int by = blockIdx.y;   // row tile 0..31
    const int tx = t & 15, ty = t >> 4;

    // staging: thread -> single row, 16 k-floats
    const int srow = t >> 1;          // 0..127
    const int kseg = (t & 1) << 4;    // 0 or 16

    // B source row (fixed per thread)
    int bsrc;
    {
        const int c = bx * 128 + srow;
        if (c < 1024)      bsrc = ((c >> 6) << 7) + (c & 63);
        else if (c < 2048) bsrc = 2048 + (((c - 1024) >> 6) << 7) + (c & 63);
        else               bsrc = 4096 + (c - 2048);
    }
    const int arow = by * 128 + srow;

    float acc[8][8];
    #pragma unroll
    for (int i = 0; i < 8; ++i)
        #pragma unroll
        for (int j = 0; j < 8; ++j) acc[i][j] = 0.f;

    for (int kt = 0; kt < 64; ++kt) {
        const int k0 = kt << 5;

        // ---- stage tile kt (global -> LDS, k-major transpose)
        float4 va[4], vb[4];
        #pragma unroll
        for (int i = 0; i < 4; ++i) {
            va[i] = *(const float4*)(x  + (size_t)arow * KDIM + k0 + kseg + (i << 2));
            vb[i] = *(const float4*)(Wc + (size_t)bsrc * KDIM + k0 + kseg + (i << 2));
        }
        #pragma unroll
        for (int i = 0; i < 4; ++i) {
            const float* pa = (const float*)&va[i];
            const float* pb = (const float*)&vb[i];
            #pragma unroll
            for (int e = 0; e < 4; ++e) {
                As[kseg + (i << 2) + e][srow] = pa[e];
                Bs[kseg + (i << 2) + e][srow] = pb[e];
            }
        }
        __syncthreads();

        // ---- compute 32 kk on the buffer
        #pragma unroll
        for (int kk = 0; kk < 32; ++kk) {
            float4 a0 = *(const float4*)(&As[kk][ty << 3]);
            float4 a1 = *(const float4*)(&As[kk][(ty << 3) + 4]);
            float4 b0 = *(const float4*)(&Bs[kk][tx << 2]);
            float4 b1 = *(const float4*)(&Bs[kk][64 + (tx << 2)]);
            const float av[8] = {a0.x, a0.y, a0.z, a0.w, a1.x, a1.y, a1.z, a1.w};
            const float bv[8] = {b0.x, b0.y, b0.z, b0.w, b1.x, b1.y, b1.z, b1.w};
            #pragma unroll
            for (int i = 0; i < 8; ++i)
                #pragma unroll
                for (int j = 0; j < 8; ++j)
                    acc[i][j] = fmaf(av[i], bv[j], acc[i][j]);
        }
        __syncthreads();
    }

    // ---- epilogue: bias + rope-scale + scatter
    float* kout = out + K_OFF;
    float* vout = out + V_OFF;
    #pragma unroll
    for (int i = 0; i < 8; ++i) {
        const int r = by * 128 + (ty << 3) + i;
        const int b = r >> 11, s = r & 2047;
        #pragma unroll
        for (int g = 0; g < 2; ++g) {
            #pragma unroll
            for (int j = 0; j < 4; ++j) {
                const int c = bx * 128 + (g << 6) + (tx << 2) + j;
                const float a = acc[i][(g << 2) + j];
                if (c < 2048) {
                    const int sec = c >> 10;
                    const int cc  = c & 1023;
                    const int h = cc >> 6, d2 = cc & 63;
                    const float val = (a + bc[sec * 2048 + h * 128 + d2]) * fq[s * 64 + d2];
                    if (sec == 0) {
                        qws[((size_t)(b * 16 + h) * 2048 + s) * 64 + d2] = 2.0f * val;
                    } else {
                        const size_t o = ((size_t)(b * 16 + h) * 2048 + s) * 128 + d2;
                        kout[o] = val; kout[o + 64] = val;
                    }
                } else {
                    const int cc = c - 2048;
                    const int h = cc >> 7, d = cc & 127;
                    vout[((size_t)(b * 16 + h) * 2048 + s) * 128 + d] = a + bc[4096 + cc];
                }
            }
        }
    }
}

// ---------------------------------------------------------------------------
// Kernel 2: register-tiled flash attention.
// R9 change: Ps is PER-WAVE (each wave's 32 q-rows are produced & consumed
// by the same wave), so the post-Ps barrier is replaced by an in-wave
// s_waitcnt lgkmcnt(0). Barriers per tile: 3 -> 2. Everything else as R8.
// ---------------------------------------------------------------------------
__global__ __launch_bounds__(256, 2) void attn_kernel(
    const float* __restrict__ qws, const float* __restrict__ kbuf,
    const float* __restrict__ vbuf, float* __restrict__ y)
{
    __shared__ __align__(16) float  Qt[64][128];
    __shared__ __align__(16) float  Kt[64][64];
    __shared__ __align__(16) __half Vs[64][128];
    __shared__ __align__(16) __half Ps[4][64][32];   // per-wave P tiles

    const int t   = threadIdx.x;
    const int bid = blockIdx.x;
    const int bh  = bid & 31;
    const int qb  = bid >> 5;
    const int tr  = t >> 4;
    const int tc  = t & 15;
    const int s0  = qb << 7;
    const int w   = t >> 6;       // wave id
    const int ltr = tr & 3;       // tr within wave

    const float* qp = qws  + (size_t)bh * (2048 * 64);
    const float* kb = kbuf + (size_t)bh * (2048 * 128);
    const float* vb = vbuf + (size_t)bh * (2048 * 128);

    const int kk0 = t >> 2, sg = t & 3;
    const int fi = t & 31, r0 = t >> 5;

    {
        const int qr = t & 127;
        const int dh = (t >> 7) << 5;
        const float* src = qp + (size_t)(s0 + qr) * 64 + dh;
        #pragma unroll
        for (int i = 0; i < 8; ++i) {
            float4 v4 = *(const float4*)(src + (i << 2));
            Qt[dh + (i << 2) + 0][qr] = v4.x;
            Qt[dh + (i << 2) + 1][qr] = v4.y;
            Qt[dh + (i << 2) + 2][qr] = v4.z;
            Qt[dh + (i << 2) + 3][qr] = v4.w;
        }
    }
    {
        #pragma unroll
        for (int i = 0; i < 4; ++i) {
            float4 k4 = *(const float4*)(kb + (size_t)kk0 * 128 + sg * 16 + (i << 2));
            Kt[sg * 16 + (i << 2) + 0][kk0] = k4.x;
            Kt[sg * 16 + (i << 2) + 1][kk0] = k4.y;
            Kt[sg * 16 + (i << 2) + 2][kk0] = k4.z;
            Kt[sg * 16 + (i << 2) + 3][kk0] = k4.w;
        }
        #pragma unroll
        for (int l = 0; l < 8; ++l) {
            const int key = r0 + (l << 3);
            float4 v4 = *(const float4*)(vb + (size_t)key * 128 + (fi << 2));
            __half2 h0 = __floats2half2_rn(v4.x, v4.y);
            __half2 h1 = __floats2half2_rn(v4.z, v4.w);
            float2 wv; ((__half2*)&wv)[0] = h0; ((__half2*)&wv)[1] = h1;
            *(float2*)(&Vs[key][fi << 2]) = wv;
        }
    }
    __syncthreads();

    float accO[8][8];
    #pragma unroll
    for (int i = 0; i < 8; ++i)
        #pragma unroll
        for (int j = 0; j < 8; ++j) accO[i][j] = 0.f;
    float mrow[8], lrow[8];
    #pragma unroll
    for (int i = 0; i < 8; ++i) { mrow[i] = -INFINITY; lrow[i] = 0.f; }

    const float scale = 0.08838834764831845f;  // 1/sqrt(128)

    for (int kt = 0; kt < 32; ++kt) {
        float4 kreg[4], vreg[8];
        if (kt < 31) {
            const size_t base = (size_t)(kt + 1) * 64 * 128;
            #pragma unroll
            for (int i = 0; i < 4; ++i)
                kreg[i] = *(const float4*)(kb + base + (size_t)kk0 * 128 + sg * 16 + (i << 2));
            #pragma unroll
            for (int l = 0; l < 8; ++l) {
                const int key = r0 + (l << 3);
                vreg[l] = *(const float4*)(vb + base + (size_t)key * 128 + (fi << 2));
            }
        }

        float sv[8][4];
        #pragma unroll
        for (int i = 0; i < 8; ++i)
            #pragma unroll
            for (int j = 0; j < 4; ++j) sv[i][j] = 0.f;

        #pragma unroll 4
        for (int d = 0; d < 64; ++d) {
            float4 a0 = *(const float4*)(&Qt[d][tr << 3]);
            float4 a1 = *(const float4*)(&Qt[d][(tr << 3) + 4]);
            float4 kv = *(const float4*)(&Kt[d][tc << 2]);
            const float av[8] = {a0.x, a0.y, a0.z, a0.w, a1.x, a1.y, a1.z, a1.w};
            const float bv[4] = {kv.x, kv.y, kv.z, kv.w};
            #pragma unroll
            for (int i = 0; i < 8; ++i)
                #pragma unroll
                for (int j = 0; j < 4; ++j)
                    sv[i][j] = fmaf(av[i], bv[j], sv[i][j]);
        }

        #pragma unroll
        for (int i = 0; i < 8; ++i) {
            #pragma unroll
            for (int j = 0; j < 4; ++j) sv[i][j] *= scale;
            float mx = fmaxf(fmaxf(sv[i][0], sv[i][1]), fmaxf(sv[i][2], sv[i][3]));
            mx = fmaxf(mx, __shfl_xor(mx, 1));
            mx = fmaxf(mx, __shfl_xor(mx, 2));
            mx = fmaxf(mx, __shfl_xor(mx, 4));
            mx = fmaxf(mx, __shfl_xor(mx, 8));
            const float mn = fmaxf(mrow[i], mx);
            const float al = __expf(mrow[i] - mn);
            mrow[i] = mn;
            float ps = 0.f;
            #pragma unroll
            for (int j = 0; j < 4; ++j) {
                const float p = __expf(sv[i][j] - mn);
                sv[i][j] = p;
                ps += p;
            }
            ps += __shfl_xor(ps, 1);
            ps += __shfl_xor(ps, 2);
            ps += __shfl_xor(ps, 4);
            ps += __shfl_xor(ps, 8);
            lrow[i] = lrow[i] * al + ps;
            #pragma unroll
            for (int j = 0; j < 8; ++j) accO[i][j] *= al;
        }

        // ---- write P (fp16) to this wave's private Ps region
        #pragma unroll
        for (int j = 0; j < 4; ++j) {
            __half2 h[4];
            #pragma unroll
            for (int q = 0; q < 4; ++q) {
                __half2 hh;
                hh.x = __float2half_rn(sv[2 * q][j]);
                hh.y = __float2half_rn(sv[2 * q + 1][j]);
                h[q] = hh;
            }
            *(float4*)(&Ps[w][(tc << 2) + j][ltr << 3]) = *(float4*)h;
        }
        // in-wave visibility: DS ops are in-order per wave; drain them.
        asm volatile("s_waitcnt lgkmcnt(0)" ::: "memory");

        // ---- step 3: O += P . V
        for (int key = 0; key < 64; ++key) {
            float4 praw = *(const float4*)(&Ps[w][key][ltr << 3]);
            const __half2* ph = (const __half2*)&praw;
            float pv[8];
            #pragma unroll
            for (int q = 0; q < 4; ++q) {
                pv[2 * q]     = __low2float(ph[q]);
                pv[2 * q + 1] = __high2float(ph[q]);
            }
            float2 vr0 = *(const float2*)(&Vs[key][tc << 2]);
            float2 vr1 = *(const float2*)(&Vs[key][64 + (tc << 2)]);
            const __half2* vh0 = (const __half2*)&vr0;
            const __half2* vh1 = (const __half2*)&vr1;
            const float vv[8] = {
                __low2float(vh0[0]), __high2float(vh0[0]),
                __low2float(vh0[1]), __high2float(vh0[1]),
                __low2float(vh1[0]), __high2float(vh1[0]),
                __low2float(vh1[1]), __high2float(vh1[1])};
            #pragma unroll
            for (int i = 0; i < 8; ++i)
                #pragma unroll
                for (int j = 0; j < 8; ++j)
                    accO[i][j] = fmaf(pv[i], vv[j], accO[i][j]);
        }

        if (kt < 31) {
            __syncthreads();
            #pragma unroll
            for (int i = 0; i < 4; ++i) {
                Kt[sg * 16 + (i << 2) + 0][kk0] = kreg[i].x;
                Kt[sg * 16 + (i << 2) + 1][kk0] = kreg[i].y;
                Kt[sg * 16 + (i << 2) + 2][kk0] = kreg[i].z;
                Kt[sg * 16 + (i << 2) + 3][kk0] = kreg[i].w;
            }
            #pragma unroll
            for (int l = 0; l < 8; ++l) {
                const int key = r0 + (l << 3);
                __half2 h0 = __floats2half2_rn(vreg[l].x, vreg[l].y);
                __half2 h1 = __floats2half2_rn(vreg[l].z, vreg[l].w);
                float2 wv; ((__half2*)&wv)[0] = h0; ((__half2*)&wv)[1] = h1;
                *(float2*)(&Vs[key][fi << 2]) = wv;
            }
            __syncthreads();
        }
    }

    const int b = bh >> 4, h = bh & 15;
    #pragma unroll
    for (int i = 0; i < 8; ++i) {
        const float inv = 1.f / lrow[i];
        const int srow = s0 + (tr << 3) + i;
        float* yp = y + ((size_t)(b * 2048 + srow)) * 2048 + h * 128;
        float4 o0, o1;
        o0.x = accO[i][0] * inv; o0.y = accO[i][1] * inv;
        o0.z = accO[i][2] * inv; o0.w = accO[i][3] * inv;
        o1.x = accO[i][4] * inv; o1.y = accO[i][5] * inv;
        o1.z = accO[i][6] * inv; o1.w = accO[i][7] * inv;
        *(float4*)(yp + (tc << 2))      = o0;
        *(float4*)(yp + 64 + (tc << 2)) = o1;
    }
}

extern "C" void kernel_launch(void* const* d_in, const int* in_sizes, int n_in,
                              void* d_out, int out_size, void* d_ws, size_t ws_size,
                              hipStream_t stream)
{
    const float* x  = (const float*)d_in[0];
    const float* Wc = (const float*)d_in[1];
    const float* bc = (const float*)d_in[2];
    const float* fq = (const float*)d_in[3];
    float* out = (float*)d_out;
    float* qws = (float*)d_ws;   // compact q, (B,H,S,64) fp32 = 16 MiB

    dim3 g1(32, 32);
    gemm_rope_kernel<<<g1, 256, 0, stream>>>(x, Wc, bc, fq, qws, out);
    attn_kernel<<<512, 256, 0, stream>>>(qws, out + K_OFF, out + V_OFF, out + Y_OFF);
}

// Round 10
// 1359.282 us; speedup vs baseline: 10.2449x; 1.1353x over previous
//
#include <hip/hip_runtime.h>
#include <hip/hip_fp16.h>
#include <math.h>

// Problem constants
#define KDIM  2048
// d_out layout (floats): y | k | v
#define Y_OFF 0
#define K_OFF 8388608
#define V_OFF 16777216

typedef _Float16 half2v __attribute__((ext_vector_type(2)));

__device__ __forceinline__ float fdot2f(half2v a, half2v b, float c) {
#if __has_builtin(__builtin_amdgcn_fdot2)
    return __builtin_amdgcn_fdot2(a, b, c, false);
#else
    return fmaf((float)a[1], (float)b[1], fmaf((float)a[0], (float)b[0], c));
#endif
}

// ---------------------------------------------------------------------------
// Kernel 1: qkv = x @ Wc^T + bc, fused with rope-scale + scatter.
// UNCHANGED from R9 (8x8 tile, BM=BN=128, BK=32, single-buffer LDS).
// ---------------------------------------------------------------------------
__global__ __launch_bounds__(256) void gemm_rope_kernel(
    const float* __restrict__ x, const float* __restrict__ Wc,
    const float* __restrict__ bc, const float* __restrict__ fq,
    float* __restrict__ qws, float* __restrict__ out)
{
    __shared__ __align__(16) float As[32][132];   // k-major, pad 132
    __shared__ __align__(16) float Bs[32][132];

    const int t  = threadIdx.x;
    const int bx = blockIdx.x;
    const int by = blockIdx.y;
    const int tx = t & 15, ty = t >> 4;

    const int srow = t >> 1;          // 0..127
    const int kseg = (t & 1) << 4;    // 0 or 16

    int bsrc;
    {
        const int c = bx * 128 + srow;
        if (c < 1024)      bsrc = ((c >> 6) << 7) + (c & 63);
        else if (c < 2048) bsrc = 2048 + (((c - 1024) >> 6) << 7) + (c & 63);
        else               bsrc = 4096 + (c - 2048);
    }
    const int arow = by * 128 + srow;

    float acc[8][8];
    #pragma unroll
    for (int i = 0; i < 8; ++i)
        #pragma unroll
        for (int j = 0; j < 8; ++j) acc[i][j] = 0.f;

    for (int kt = 0; kt < 64; ++kt) {
        const int k0 = kt << 5;

        float4 va[4], vb[4];
        #pragma unroll
        for (int i = 0; i < 4; ++i) {
            va[i] = *(const float4*)(x  + (size_t)arow * KDIM + k0 + kseg + (i << 2));
            vb[i] = *(const float4*)(Wc + (size_t)bsrc * KDIM + k0 + kseg + (i << 2));
        }
        #pragma unroll
        for (int i = 0; i < 4; ++i) {
            const float* pa = (const float*)&va[i];
            const float* pb = (const float*)&vb[i];
            #pragma unroll
            for (int e = 0; e < 4; ++e) {
                As[kseg + (i << 2) + e][srow] = pa[e];
                Bs[kseg + (i << 2) + e][srow] = pb[e];
            }
        }
        __syncthreads();

        #pragma unroll
        for (int kk = 0; kk < 32; ++kk) {
            float4 a0 = *(const float4*)(&As[kk][ty << 3]);
            float4 a1 = *(const float4*)(&As[kk][(ty << 3) + 4]);
            float4 b0 = *(const float4*)(&Bs[kk][tx << 2]);
            float4 b1 = *(const float4*)(&Bs[kk][64 + (tx << 2)]);
            const float av[8] = {a0.x, a0.y, a0.z, a0.w, a1.x, a1.y, a1.z, a1.w};
            const float bv[8] = {b0.x, b0.y, b0.z, b0.w, b1.x, b1.y, b1.z, b1.w};
            #pragma unroll
            for (int i = 0; i < 8; ++i)
                #pragma unroll
                for (int j = 0; j < 8; ++j)
                    acc[i][j] = fmaf(av[i], bv[j], acc[i][j]);
        }
        __syncthreads();
    }

    float* kout = out + K_OFF;
    float* vout = out + V_OFF;
    #pragma unroll
    for (int i = 0; i < 8; ++i) {
        const int r = by * 128 + (ty << 3) + i;
        const int b = r >> 11, s = r & 2047;
        #pragma unroll
        for (int g = 0; g < 2; ++g) {
            #pragma unroll
            for (int j = 0; j < 4; ++j) {
                const int c = bx * 128 + (g << 6) + (tx << 2) + j;
                const float a = acc[i][(g << 2) + j];
                if (c < 2048) {
                    const int sec = c >> 10;
                    const int cc  = c & 1023;
                    const int h = cc >> 6, d2 = cc & 63;
                    const float val = (a + bc[sec * 2048 + h * 128 + d2]) * fq[s * 64 + d2];
                    if (sec == 0) {
                        qws[((size_t)(b * 16 + h) * 2048 + s) * 64 + d2] = 2.0f * val;
                    } else {
                        const size_t o = ((size_t)(b * 16 + h) * 2048 + s) * 128 + d2;
                        kout[o] = val; kout[o + 64] = val;
                    }
                } else {
                    const int cc = c - 2048;
                    const int h = cc >> 7, d = cc & 127;
                    vout[((size_t)(b * 16 + h) * 2048 + s) * 128 + d] = a + bc[4096 + cc];
                }
            }
        }
    }
}

// ---------------------------------------------------------------------------
// Kernel 2: register-tiled flash attention, PV via v_dot2_f32_f16.
// LDS (80 KB exactly -> 2 blocks/CU):
//   Qt[64 d][128 qr] fp32 32KB | Kt[64 d][64 key] fp32 16KB |
//   Vt[128 d][64 key] fp16 16KB (XOR-swz ((d>>2)&7)<<3) |
//   Ps[4 wave][32 q][64 key] fp16 16KB (XOR-swz ltr<<3)
// PV: O[i][e] += dot2(P2, V2) — 2 MACs/inst fp32-accum, zero unpack cvts.
// ---------------------------------------------------------------------------
__global__ __launch_bounds__(256, 2) void attn_kernel(
    const float* __restrict__ qws, const float* __restrict__ kbuf,
    const float* __restrict__ vbuf, float* __restrict__ y)
{
    __shared__ __align__(16) float  Qt[64][128];
    __shared__ __align__(16) float  Kt[64][64];
    __shared__ __align__(16) __half Vt[128][64];
    __shared__ __align__(16) __half Ps[4][32][64];

    const int t   = threadIdx.x;
    const int bid = blockIdx.x;
    const int bh  = bid & 31;
    const int qb  = bid >> 5;
    const int tr  = t >> 4;
    const int tc  = t & 15;
    const int s0  = qb << 7;
    const int wid = t >> 6;
    const int ltr = tr & 3;

    const float* qp = qws  + (size_t)bh * (2048 * 64);
    const float* kb = kbuf + (size_t)bh * (2048 * 128);
    const float* vb = vbuf + (size_t)bh * (2048 * 128);

    // K staging map: key kk0, d-segment sg (16 floats)
    const int kk0 = t >> 2, sg = t & 3;
    // V staging map: key-pair kp, d-segment ds0 (16 d)
    const int kp  = t >> 3;          // 0..31
    const int ds0 = (t & 7) << 4;    // 0..112

    // ---- stage Q transposed (compact 64-d)
    {
        const int qr = t & 127;
        const int dh = (t >> 7) << 5;
        const float* src = qp + (size_t)(s0 + qr) * 64 + dh;
        #pragma unroll
        for (int i = 0; i < 8; ++i) {
            float4 v4 = *(const float4*)(src + (i << 2));
            Qt[dh + (i << 2) + 0][qr] = v4.x;
            Qt[dh + (i << 2) + 1][qr] = v4.y;
            Qt[dh + (i << 2) + 2][qr] = v4.z;
            Qt[dh + (i << 2) + 3][qr] = v4.w;
        }
    }
    // ---- stage K/V tile 0
    {
        #pragma unroll
        for (int i = 0; i < 4; ++i) {
            float4 k4 = *(const float4*)(kb + (size_t)kk0 * 128 + sg * 16 + (i << 2));
            Kt[sg * 16 + (i << 2) + 0][kk0] = k4.x;
            Kt[sg * 16 + (i << 2) + 1][kk0] = k4.y;
            Kt[sg * 16 + (i << 2) + 2][kk0] = k4.z;
            Kt[sg * 16 + (i << 2) + 3][kk0] = k4.w;
        }
        #pragma unroll
        for (int u = 0; u < 4; ++u) {
            float4 v0 = *(const float4*)(vb + (size_t)(2 * kp) * 128 + ds0 + (u << 2));
            float4 v1 = *(const float4*)(vb + (size_t)(2 * kp + 1) * 128 + ds0 + (u << 2));
            const float* p0 = (const float*)&v0;
            const float* p1 = (const float*)&v1;
            #pragma unroll
            for (int e = 0; e < 4; ++e) {
                const int d = ds0 + (u << 2) + e;
                const int off = (2 * kp) ^ (((d >> 2) & 7) << 3);
                half2v h; h[0] = (_Float16)p0[e]; h[1] = (_Float16)p1[e];
                *reinterpret_cast<half2v*>(&Vt[d][off]) = h;
            }
        }
    }
    __syncthreads();

    float accO[8][8];
    #pragma unroll
    for (int i = 0; i < 8; ++i)
        #pragma unroll
        for (int j = 0; j < 8; ++j) accO[i][j] = 0.f;
    float mrow[8], lrow[8];
    #pragma unroll
    for (int i = 0; i < 8; ++i) { mrow[i] = -INFINITY; lrow[i] = 0.f; }

    const float scale = 0.08838834764831845f;  // 1/sqrt(128)
    const int   pvs   = (tc & 7) << 3;         // V swizzle for this thread's d-rows
    const int   pss   = ltr << 3;              // Ps swizzle for this wave-row group

    for (int kt = 0; kt < 32; ++kt) {
        // ---- prefetch next tile's K/V into registers
        float4 kreg[4], vr0[4], vr1[4];
        if (kt < 31) {
            const size_t base = (size_t)(kt + 1) * 64 * 128;
            #pragma unroll
            for (int i = 0; i < 4; ++i)
                kreg[i] = *(const float4*)(kb + base + (size_t)kk0 * 128 + sg * 16 + (i << 2));
            #pragma unroll
            for (int u = 0; u < 4; ++u) {
                vr0[u] = *(const float4*)(vb + base + (size_t)(2 * kp) * 128 + ds0 + (u << 2));
                vr1[u] = *(const float4*)(vb + base + (size_t)(2 * kp + 1) * 128 + ds0 + (u << 2));
            }
        }

        // ---- step 1: S[8][4] = Qc . Kc^T over 64 compact dims (fp32)
        float sv[8][4];
        #pragma unroll
        for (int i = 0; i < 8; ++i)
            #pragma unroll
            for (int j = 0; j < 4; ++j) sv[i][j] = 0.f;

        #pragma unroll 4
        for (int d = 0; d < 64; ++d) {
            float4 a0 = *(const float4*)(&Qt[d][tr << 3]);
            float4 a1 = *(const float4*)(&Qt[d][(tr << 3) + 4]);
            float4 kv = *(const float4*)(&Kt[d][tc << 2]);
            const float av[8] = {a0.x, a0.y, a0.z, a0.w, a1.x, a1.y, a1.z, a1.w};
            const float bv[4] = {kv.x, kv.y, kv.z, kv.w};
            #pragma unroll
            for (int i = 0; i < 8; ++i)
                #pragma unroll
                for (int j = 0; j < 4; ++j)
                    sv[i][j] = fmaf(av[i], bv[j], sv[i][j]);
        }

        // ---- softmax update (skip rescale when max unchanged: al==1 exactly)
        #pragma unroll
        for (int i = 0; i < 8; ++i) {
            #pragma unroll
            for (int j = 0; j < 4; ++j) sv[i][j] *= scale;
            float mx = fmaxf(fmaxf(sv[i][0], sv[i][1]), fmaxf(sv[i][2], sv[i][3]));
            mx = fmaxf(mx, __shfl_xor(mx, 1));
            mx = fmaxf(mx, __shfl_xor(mx, 2));
            mx = fmaxf(mx, __shfl_xor(mx, 4));
            mx = fmaxf(mx, __shfl_xor(mx, 8));
            if (mx > mrow[i]) {
                const float al = __expf(mrow[i] - mx);   // 0 on first tile
                mrow[i] = mx;
                lrow[i] *= al;
                #pragma unroll
                for (int j = 0; j < 8; ++j) accO[i][j] *= al;
            }
            float ps = 0.f;
            #pragma unroll
            for (int j = 0; j < 4; ++j) {
                const float p = __expf(sv[i][j] - mrow[i]);
                sv[i][j] = p;
                ps += p;
            }
            ps += __shfl_xor(ps, 1);
            ps += __shfl_xor(ps, 2);
            ps += __shfl_xor(ps, 4);
            ps += __shfl_xor(ps, 8);
            lrow[i] += ps;
        }

        // ---- write P (fp16 pairs) to this wave's Ps, swizzled
        #pragma unroll
        for (int i = 0; i < 8; ++i) {
            half2v h0; h0[0] = (_Float16)sv[i][0]; h0[1] = (_Float16)sv[i][1];
            half2v h1; h1[0] = (_Float16)sv[i][2]; h1[1] = (_Float16)sv[i][3];
            uint2 wv;
            wv.x = __builtin_bit_cast(unsigned int, h0);
            wv.y = __builtin_bit_cast(unsigned int, h1);
            *reinterpret_cast<uint2*>(&Ps[wid][(ltr << 3) + i][(tc << 2) ^ pss]) = wv;
        }
        asm volatile("s_waitcnt lgkmcnt(0)" ::: "memory");

        // ---- step 3: O += P . V via dot2 (8-key chunks)
        for (int c = 0; c < 8; ++c) {
            uint4 vvu[8];
            #pragma unroll
            for (int e = 0; e < 8; ++e) {
                const int d = (e < 4) ? (tc << 2) + e : 64 + (tc << 2) + (e - 4);
                vvu[e] = *reinterpret_cast<const uint4*>(&Vt[d][(c << 3) ^ pvs]);
            }
            #pragma unroll
            for (int i = 0; i < 8; ++i) {
                uint4 ppu = *reinterpret_cast<const uint4*>(
                    &Ps[wid][(ltr << 3) + i][(c << 3) ^ pss]);
                const half2v* ph = reinterpret_cast<const half2v*>(&ppu);
                #pragma unroll
                for (int e = 0; e < 8; ++e) {
                    const half2v* vh = reinterpret_cast<const half2v*>(&vvu[e]);
                    float a = accO[i][e];
                    a = fdot2f(ph[0], vh[0], a);
                    a = fdot2f(ph[1], vh[1], a);
                    a = fdot2f(ph[2], vh[2], a);
                    a = fdot2f(ph[3], vh[3], a);
                    accO[i][e] = a;
                }
            }
        }

        // ---- commit staged K/V for next tile
        if (kt < 31) {
            __syncthreads();
            #pragma unroll
            for (int i = 0; i < 4; ++i) {
                Kt[sg * 16 + (i << 2) + 0][kk0] = kreg[i].x;
                Kt[sg * 16 + (i << 2) + 1][kk0] = kreg[i].y;
                Kt[sg * 16 + (i << 2) + 2][kk0] = kreg[i].z;
                Kt[sg * 16 + (i << 2) + 3][kk0] = kreg[i].w;
            }
            #pragma unroll
            for (int u = 0; u < 4; ++u) {
                const float* p0 = (const float*)&vr0[u];
                const float* p1 = (const float*)&vr1[u];
                #pragma unroll
                for (int e = 0; e < 4; ++e) {
                    const int d = ds0 + (u << 2) + e;
                    const int off = (2 * kp) ^ (((d >> 2) & 7) << 3);
                    half2v h; h[0] = (_Float16)p0[e]; h[1] = (_Float16)p1[e];
                    *reinterpret_cast<half2v*>(&Vt[d][off]) = h;
                }
            }
            __syncthreads();
        }
    }

    // ---- epilogue
    const int b = bh >> 4, h = bh & 15;
    #pragma unroll
    for (int i = 0; i < 8; ++i) {
        const float inv = 1.f / lrow[i];
        const int srow = s0 + (tr << 3) + i;
        float* yp = y + ((size_t)(b * 2048 + srow)) * 2048 + h * 128;
        float4 o0, o1;
        o0.x = accO[i][0] * inv; o0.y = accO[i][1] * inv;
        o0.z = accO[i][2] * inv; o0.w = accO[i][3] * inv;
        o1.x = accO[i][4] * inv; o1.y = accO[i][5] * inv;
        o1.z = accO[i][6] * inv; o1.w = accO[i][7] * inv;
        *(float4*)(yp + (tc << 2))      = o0;
        *(float4*)(yp + 64 + (tc << 2)) = o1;
    }
}

extern "C" void kernel_launch(void* const* d_in, const int* in_sizes, int n_in,
                              void* d_out, int out_size, void* d_ws, size_t ws_size,
                              hipStream_t stream)
{
    const float* x  = (const float*)d_in[0];
    const float* Wc = (const float*)d_in[1];
    const float* bc = (const float*)d_in[2];
    const float* fq = (const float*)d_in[3];
    float* out = (float*)d_out;
    float* qws = (float*)d_ws;   // compact q, (B,H,S,64) fp32 = 16 MiB

    dim3 g1(32, 32);
    gemm_rope_kernel<<<g1, 256, 0, stream>>>(x, Wc, bc, fq, qws, out);
    attn_kernel<<<512, 256, 0, stream>>>(qws, out + K_OFF, out + V_OFF, out + Y_OFF);
}

// Round 12
// 1265.836 us; speedup vs baseline: 11.0012x; 1.0738x over previous
//
#include <hip/hip_runtime.h>
#include <hip/hip_fp16.h>
#include <math.h>

// Problem constants
#define KDIM  2048
// d_out layout (floats): y | k | v
#define Y_OFF 0
#define K_OFF 8388608
#define V_OFF 16777216

typedef _Float16 half2v __attribute__((ext_vector_type(2)));

__device__ __forceinline__ float fdot2f(half2v a, half2v b, float c) {
#if __has_builtin(__builtin_amdgcn_fdot2)
    return __builtin_amdgcn_fdot2(a, b, c, false);
#else
    return fmaf((float)a[1], (float)b[1], fmaf((float)a[0], (float)b[0], c));
#endif
}

// ---------------------------------------------------------------------------
// Kernel 1a: q,k columns (0..2047 reduced) = fp32 path (argmax-critical).
// 8x8 tile, BM=BN=128, BK=32, single-buffer LDS. Same as R10's gemm.
// ---------------------------------------------------------------------------
__global__ __launch_bounds__(256) void gemm_qk_kernel(
    const float* __restrict__ x, const float* __restrict__ Wc,
    const float* __restrict__ bc, const float* __restrict__ fq,
    float* __restrict__ qws, float* __restrict__ out)
{
    __shared__ __align__(16) float As[32][132];   // k-major, pad 132
    __shared__ __align__(16) float Bs[32][132];

    const int t  = threadIdx.x;
    const int bx = blockIdx.x;   // 0..15 -> cols 0..2047
    const int by = blockIdx.y;
    const int tx = t & 15, ty = t >> 4;

    const int srow = t >> 1;          // 0..127
    const int kseg = (t & 1) << 4;    // 0 or 16

    int bsrc;
    {
        const int c = bx * 128 + srow;
        if (c < 1024) bsrc = ((c >> 6) << 7) + (c & 63);
        else          bsrc = 2048 + (((c - 1024) >> 6) << 7) + (c & 63);
    }
    const int arow = by * 128 + srow;

    float acc[8][8];
    #pragma unroll
    for (int i = 0; i < 8; ++i)
        #pragma unroll
        for (int j = 0; j < 8; ++j) acc[i][j] = 0.f;

    for (int kt = 0; kt < 64; ++kt) {
        const int k0 = kt << 5;

        float4 va[4], vb[4];
        #pragma unroll
        for (int i = 0; i < 4; ++i) {
            va[i] = *(const float4*)(x  + (size_t)arow * KDIM + k0 + kseg + (i << 2));
            vb[i] = *(const float4*)(Wc + (size_t)bsrc * KDIM + k0 + kseg + (i << 2));
        }
        #pragma unroll
        for (int i = 0; i < 4; ++i) {
            const float* pa = (const float*)&va[i];
            const float* pb = (const float*)&vb[i];
            #pragma unroll
            for (int e = 0; e < 4; ++e) {
                As[kseg + (i << 2) + e][srow] = pa[e];
                Bs[kseg + (i << 2) + e][srow] = pb[e];
            }
        }
        __syncthreads();

        #pragma unroll
        for (int kk = 0; kk < 32; ++kk) {
            float4 a0 = *(const float4*)(&As[kk][ty << 3]);
            float4 a1 = *(const float4*)(&As[kk][(ty << 3) + 4]);
            float4 b0 = *(const float4*)(&Bs[kk][tx << 2]);
            float4 b1 = *(const float4*)(&Bs[kk][64 + (tx << 2)]);
            const float av[8] = {a0.x, a0.y, a0.z, a0.w, a1.x, a1.y, a1.z, a1.w};
            const float bv[8] = {b0.x, b0.y, b0.z, b0.w, b1.x, b1.y, b1.z, b1.w};
            #pragma unroll
            for (int i = 0; i < 8; ++i)
                #pragma unroll
                for (int j = 0; j < 8; ++j)
                    acc[i][j] = fmaf(av[i], bv[j], acc[i][j]);
        }
        __syncthreads();
    }

    float* kout = out + K_OFF;
    #pragma unroll
    for (int i = 0; i < 8; ++i) {
        const int r = by * 128 + (ty << 3) + i;
        const int b = r >> 11, s = r & 2047;
        #pragma unroll
        for (int g = 0; g < 2; ++g) {
            #pragma unroll
            for (int j = 0; j < 4; ++j) {
                const int c = bx * 128 + (g << 6) + (tx << 2) + j;
                const float a = acc[i][(g << 2) + j];
                const int sec = c >> 10;          // 0=q, 1=k
                const int cc  = c & 1023;
                const int h = cc >> 6, d2 = cc & 63;
                const float val = (a + bc[sec * 2048 + h * 128 + d2]) * fq[s * 64 + d2];
                if (sec == 0) {
                    qws[((size_t)(b * 16 + h) * 2048 + s) * 64 + d2] = 2.0f * val;
                } else {
                    const size_t o = ((size_t)(b * 16 + h) * 2048 + s) * 128 + d2;
                    kout[o] = val; kout[o + 64] = val;
                }
            }
        }
    }
}

// ---------------------------------------------------------------------------
// Kernel 1b: v columns via fp16-pair dot2 (2 MACs/inst, fp32 accum).
// R11 BUGFIX: A-frag = TWO uint4 (8 half2v = 32B), B-frag = uint4 (4 half2v
// = 16B). R11 used uint4/uint2 and indexed past them -> garbage/NaN.
// ---------------------------------------------------------------------------
__global__ __launch_bounds__(256) void gemm_v_kernel(
    const float* __restrict__ x, const float* __restrict__ Wc,
    const float* __restrict__ bc, float* __restrict__ out)
{
    __shared__ __align__(16) half2v As2[16][132];  // [k-pair][row]
    __shared__ __align__(16) half2v Bs2[16][132];

    const int t  = threadIdx.x;
    const int bx = blockIdx.x;   // 0..15 -> v cols bx*128..+127
    const int by = blockIdx.y;
    const int tx = t & 15, ty = t >> 4;

    const int srow = t >> 1;          // 0..127
    const int kseg = (t & 1) << 4;    // 0 or 16
    const int kp0  = (t & 1) << 3;    // pair base 0 or 8

    const int arow = by * 128 + srow;
    const int vsrc = 4096 + bx * 128 + srow;   // Wc row for v

    float acc[8][8];
    #pragma unroll
    for (int i = 0; i < 8; ++i)
        #pragma unroll
        for (int j = 0; j < 8; ++j) acc[i][j] = 0.f;

    for (int kt = 0; kt < 64; ++kt) {
        const int k0 = kt << 5;

        float4 va[4], vb[4];
        #pragma unroll
        for (int i = 0; i < 4; ++i) {
            va[i] = *(const float4*)(x  + (size_t)arow * KDIM + k0 + kseg + (i << 2));
            vb[i] = *(const float4*)(Wc + (size_t)vsrc * KDIM + k0 + kseg + (i << 2));
        }
        #pragma unroll
        for (int i = 0; i < 4; ++i) {
            const float* pa = (const float*)&va[i];
            const float* pb = (const float*)&vb[i];
            #pragma unroll
            for (int e = 0; e < 2; ++e) {
                half2v ha; ha[0] = (_Float16)pa[2 * e]; ha[1] = (_Float16)pa[2 * e + 1];
                half2v hb; hb[0] = (_Float16)pb[2 * e]; hb[1] = (_Float16)pb[2 * e + 1];
                As2[kp0 + (i << 1) + e][srow] = ha;
                Bs2[kp0 + (i << 1) + e][srow] = hb;
            }
        }
        __syncthreads();

        #pragma unroll
        for (int kp = 0; kp < 16; ++kp) {
            // A-frag: 8 rows = 8 half2v = 32B -> two b128 (broadcast over tc)
            uint4 au0 = *reinterpret_cast<const uint4*>(&As2[kp][ty << 3]);
            uint4 au1 = *reinterpret_cast<const uint4*>(&As2[kp][(ty << 3) + 4]);
            const half2v* a2lo = reinterpret_cast<const half2v*>(&au0);
            const half2v* a2hi = reinterpret_cast<const half2v*>(&au1);
            // B-frag: 4 cols = 4 half2v = 16B each (banks 4tx..4tx+3, 2-way free)
            uint4 bu0 = *reinterpret_cast<const uint4*>(&Bs2[kp][tx << 2]);
            uint4 bu1 = *reinterpret_cast<const uint4*>(&Bs2[kp][64 + (tx << 2)]);
            const half2v* b0 = reinterpret_cast<const half2v*>(&bu0);
            const half2v* b1 = reinterpret_cast<const half2v*>(&bu1);
            #pragma unroll
            for (int i = 0; i < 8; ++i) {
                const half2v ai = (i < 4) ? a2lo[i] : a2hi[i - 4];
                #pragma unroll
                for (int j = 0; j < 4; ++j) {
                    acc[i][j]     = fdot2f(ai, b0[j], acc[i][j]);
                    acc[i][4 + j] = fdot2f(ai, b1[j], acc[i][4 + j]);
                }
            }
        }
        __syncthreads();
    }

    float* vout = out + V_OFF;
    #pragma unroll
    for (int i = 0; i < 8; ++i) {
        const int r = by * 128 + (ty << 3) + i;
        const int b = r >> 11, s = r & 2047;
        #pragma unroll
        for (int g = 0; g < 2; ++g) {
            #pragma unroll
            for (int j = 0; j < 4; ++j) {
                const int cc = bx * 128 + (g << 6) + (tx << 2) + j;  // 0..2047
                const int h = cc >> 7, d = cc & 127;
                vout[((size_t)(b * 16 + h) * 2048 + s) * 128 + d] =
                    acc[i][(g << 2) + j] + bc[4096 + cc];
            }
        }
    }
}

// ---------------------------------------------------------------------------
// Kernel 2: register-tiled flash attention, PV via v_dot2_f32_f16
// (unchanged from R10, ~470 us).
// ---------------------------------------------------------------------------
__global__ __launch_bounds__(256, 2) void attn_kernel(
    const float* __restrict__ qws, const float* __restrict__ kbuf,
    const float* __restrict__ vbuf, float* __restrict__ y)
{
    __shared__ __align__(16) float  Qt[64][128];
    __shared__ __align__(16) float  Kt[64][64];
    __shared__ __align__(16) __half Vt[128][64];
    __shared__ __align__(16) __half Ps[4][32][64];

    const int t   = threadIdx.x;
    const int bid = blockIdx.x;
    const int bh  = bid & 31;
    const int qb  = bid >> 5;
    const int tr  = t >> 4;
    const int tc  = t & 15;
    const int s0  = qb << 7;
    const int wid = t >> 6;
    const int ltr = tr & 3;

    const float* qp = qws  + (size_t)bh * (2048 * 64);
    const float* kb = kbuf + (size_t)bh * (2048 * 128);
    const float* vb = vbuf + (size_t)bh * (2048 * 128);

    const int kk0 = t >> 2, sg = t & 3;
    const int kp  = t >> 3;
    const int ds0 = (t & 7) << 4;

    {
        const int qr = t & 127;
        const int dh = (t >> 7) << 5;
        const float* src = qp + (size_t)(s0 + qr) * 64 + dh;
        #pragma unroll
        for (int i = 0; i < 8; ++i) {
            float4 v4 = *(const float4*)(src + (i << 2));
            Qt[dh + (i << 2) + 0][qr] = v4.x;
            Qt[dh + (i << 2) + 1][qr] = v4.y;
            Qt[dh + (i << 2) + 2][qr] = v4.z;
            Qt[dh + (i << 2) + 3][qr] = v4.w;
        }
    }
    {
        #pragma unroll
        for (int i = 0; i < 4; ++i) {
            float4 k4 = *(const float4*)(kb + (size_t)kk0 * 128 + sg * 16 + (i << 2));
            Kt[sg * 16 + (i << 2) + 0][kk0] = k4.x;
            Kt[sg * 16 + (i << 2) + 1][kk0] = k4.y;
            Kt[sg * 16 + (i << 2) + 2][kk0] = k4.z;
            Kt[sg * 16 + (i << 2) + 3][kk0] = k4.w;
        }
        #pragma unroll
        for (int u = 0; u < 4; ++u) {
            float4 v0 = *(const float4*)(vb + (size_t)(2 * kp) * 128 + ds0 + (u << 2));
            float4 v1 = *(const float4*)(vb + (size_t)(2 * kp + 1) * 128 + ds0 + (u << 2));
            const float* p0 = (const float*)&v0;
            const float* p1 = (const float*)&v1;
            #pragma unroll
            for (int e = 0; e < 4; ++e) {
                const int d = ds0 + (u << 2) + e;
                const int off = (2 * kp) ^ (((d >> 2) & 7) << 3);
                half2v h; h[0] = (_Float16)p0[e]; h[1] = (_Float16)p1[e];
                *reinterpret_cast<half2v*>(&Vt[d][off]) = h;
            }
        }
    }
    __syncthreads();

    float accO[8][8];
    #pragma unroll
    for (int i = 0; i < 8; ++i)
        #pragma unroll
        for (int j = 0; j < 8; ++j) accO[i][j] = 0.f;
    float mrow[8], lrow[8];
    #pragma unroll
    for (int i = 0; i < 8; ++i) { mrow[i] = -INFINITY; lrow[i] = 0.f; }

    const float scale = 0.08838834764831845f;  // 1/sqrt(128)
    const int   pvs   = (tc & 7) << 3;
    const int   pss   = ltr << 3;

    for (int kt = 0; kt < 32; ++kt) {
        float4 kreg[4], vr0[4], vr1[4];
        if (kt < 31) {
            const size_t base = (size_t)(kt + 1) * 64 * 128;
            #pragma unroll
            for (int i = 0; i < 4; ++i)
                kreg[i] = *(const float4*)(kb + base + (size_t)kk0 * 128 + sg * 16 + (i << 2));
            #pragma unroll
            for (int u = 0; u < 4; ++u) {
                vr0[u] = *(const float4*)(vb + base + (size_t)(2 * kp) * 128 + ds0 + (u << 2));
                vr1[u] = *(const float4*)(vb + base + (size_t)(2 * kp + 1) * 128 + ds0 + (u << 2));
            }
        }

        float sv[8][4];
        #pragma unroll
        for (int i = 0; i < 8; ++i)
            #pragma unroll
            for (int j = 0; j < 4; ++j) sv[i][j] = 0.f;

        #pragma unroll 4
        for (int d = 0; d < 64; ++d) {
            float4 a0 = *(const float4*)(&Qt[d][tr << 3]);
            float4 a1 = *(const float4*)(&Qt[d][(tr << 3) + 4]);
            float4 kv = *(const float4*)(&Kt[d][tc << 2]);
            const float av[8] = {a0.x, a0.y, a0.z, a0.w, a1.x, a1.y, a1.z, a1.w};
            const float bv[4] = {kv.x, kv.y, kv.z, kv.w};
            #pragma unroll
            for (int i = 0; i < 8; ++i)
                #pragma unroll
                for (int j = 0; j < 4; ++j)
                    sv[i][j] = fmaf(av[i], bv[j], sv[i][j]);
        }

        #pragma unroll
        for (int i = 0; i < 8; ++i) {
            #pragma unroll
            for (int j = 0; j < 4; ++j) sv[i][j] *= scale;
            float mx = fmaxf(fmaxf(sv[i][0], sv[i][1]), fmaxf(sv[i][2], sv[i][3]));
            mx = fmaxf(mx, __shfl_xor(mx, 1));
            mx = fmaxf(mx, __shfl_xor(mx, 2));
            mx = fmaxf(mx, __shfl_xor(mx, 4));
            mx = fmaxf(mx, __shfl_xor(mx, 8));
            if (mx > mrow[i]) {
                const float al = __expf(mrow[i] - mx);
                mrow[i] = mx;
                lrow[i] *= al;
                #pragma unroll
                for (int j = 0; j < 8; ++j) accO[i][j] *= al;
            }
            float ps = 0.f;
            #pragma unroll
            for (int j = 0; j < 4; ++j) {
                const float p = __expf(sv[i][j] - mrow[i]);
                sv[i][j] = p;
                ps += p;
            }
            ps += __shfl_xor(ps, 1);
            ps += __shfl_xor(ps, 2);
            ps += __shfl_xor(ps, 4);
            ps += __shfl_xor(ps, 8);
            lrow[i] += ps;
        }

        #pragma unroll
        for (int i = 0; i < 8; ++i) {
            half2v h0; h0[0] = (_Float16)sv[i][0]; h0[1] = (_Float16)sv[i][1];
            half2v h1; h1[0] = (_Float16)sv[i][2]; h1[1] = (_Float16)sv[i][3];
            uint2 wv;
            wv.x = __builtin_bit_cast(unsigned int, h0);
            wv.y = __builtin_bit_cast(unsigned int, h1);
            *reinterpret_cast<uint2*>(&Ps[wid][(ltr << 3) + i][(tc << 2) ^ pss]) = wv;
        }
        asm volatile("s_waitcnt lgkmcnt(0)" ::: "memory");

        for (int c = 0; c < 8; ++c) {
            uint4 vvu[8];
            #pragma unroll
            for (int e = 0; e < 8; ++e) {
                const int d = (e < 4) ? (tc << 2) + e : 64 + (tc << 2) + (e - 4);
                vvu[e] = *reinterpret_cast<const uint4*>(&Vt[d][(c << 3) ^ pvs]);
            }
            #pragma unroll
            for (int i = 0; i < 8; ++i) {
                uint4 ppu = *reinterpret_cast<const uint4*>(
                    &Ps[wid][(ltr << 3) + i][(c << 3) ^ pss]);
                const half2v* ph = reinterpret_cast<const half2v*>(&ppu);
                #pragma unroll
                for (int e = 0; e < 8; ++e) {
                    const half2v* vh = reinterpret_cast<const half2v*>(&vvu[e]);
                    float a = accO[i][e];
                    a = fdot2f(ph[0], vh[0], a);
                    a = fdot2f(ph[1], vh[1], a);
                    a = fdot2f(ph[2], vh[2], a);
                    a = fdot2f(ph[3], vh[3], a);
                    accO[i][e] = a;
                }
            }
        }

        if (kt < 31) {
            __syncthreads();
            #pragma unroll
            for (int i = 0; i < 4; ++i) {
                Kt[sg * 16 + (i << 2) + 0][kk0] = kreg[i].x;
                Kt[sg * 16 + (i << 2) + 1][kk0] = kreg[i].y;
                Kt[sg * 16 + (i << 2) + 2][kk0] = kreg[i].z;
                Kt[sg * 16 + (i << 2) + 3][kk0] = kreg[i].w;
            }
            #pragma unroll
            for (int u = 0; u < 4; ++u) {
                const float* p0 = (const float*)&vr0[u];
                const float* p1 = (const float*)&vr1[u];
                #pragma unroll
                for (int e = 0; e < 4; ++e) {
                    const int d = ds0 + (u << 2) + e;
                    const int off = (2 * kp) ^ (((d >> 2) & 7) << 3);
                    half2v h; h[0] = (_Float16)p0[e]; h[1] = (_Float16)p1[e];
                    *reinterpret_cast<half2v*>(&Vt[d][off]) = h;
                }
            }
            __syncthreads();
        }
    }

    const int b = bh >> 4, h = bh & 15;
    #pragma unroll
    for (int i = 0; i < 8; ++i) {
        const float inv = 1.f / lrow[i];
        const int srow = s0 + (tr << 3) + i;
        float* yp = y + ((size_t)(b * 2048 + srow)) * 2048 + h * 128;
        float4 o0, o1;
        o0.x = accO[i][0] * inv; o0.y = accO[i][1] * inv;
        o0.z = accO[i][2] * inv; o0.w = accO[i][3] * inv;
        o1.x = accO[i][4] * inv; o1.y = accO[i][5] * inv;
        o1.z = accO[i][6] * inv; o1.w = accO[i][7] * inv;
        *(float4*)(yp + (tc << 2))      = o0;
        *(float4*)(yp + 64 + (tc << 2)) = o1;
    }
}

extern "C" void kernel_launch(void* const* d_in, const int* in_sizes, int n_in,
                              void* d_out, int out_size, void* d_ws, size_t ws_size,
                              hipStream_t stream)
{
    const float* x  = (const float*)d_in[0];
    const float* Wc = (const float*)d_in[1];
    const float* bc = (const float*)d_in[2];
    const float* fq = (const float*)d_in[3];
    float* out = (float*)d_out;
    float* qws = (float*)d_ws;   // compact q, (B,H,S,64) fp32 = 16 MiB

    dim3 gqk(16, 32);
    dim3 gv(16, 32);
    gemm_qk_kernel<<<gqk, 256, 0, stream>>>(x, Wc, bc, fq, qws, out);
    gemm_v_kernel<<<gv, 256, 0, stream>>>(x, Wc, bc, out);
    attn_kernel<<<512, 256, 0, stream>>>(qws, out + K_OFF, out + V_OFF, out + Y_OFF);
}

// Round 13
// 1216.570 us; speedup vs baseline: 11.4467x; 1.0405x over previous
//
#include <hip/hip_runtime.h>
#include <hip/hip_fp16.h>
#include <math.h>

// Problem constants
#define KDIM  2048
// d_out layout (floats): y | k | v
#define Y_OFF 0
#define K_OFF 8388608
#define V_OFF 16777216

typedef _Float16 half2v __attribute__((ext_vector_type(2)));

__device__ __forceinline__ float fdot2f(half2v a, half2v b, float c) {
#if __has_builtin(__builtin_amdgcn_fdot2)
    return __builtin_amdgcn_fdot2(a, b, c, false);
#else
    return fmaf((float)a[1], (float)b[1], fmaf((float)a[0], (float)b[0], c));
#endif
}

// ---------------------------------------------------------------------------
// Kernel 1 (merged): even blocks run the fp32 qk path (LDS-bound), odd
// blocks run the fp16-dot2 v path (VALU-bound). Co-residency on a CU lets
// the v path's VALU work fill the qk path's LDS-stall shadow.
// LDS = union: qk needs 33.8 KB (fp32 As/Bs), v needs 16.9 KB (half2).
// ---------------------------------------------------------------------------
__global__ __launch_bounds__(256) void gemm_merged_kernel(
    const float* __restrict__ x, const float* __restrict__ Wc,
    const float* __restrict__ bc, const float* __restrict__ fq,
    float* __restrict__ qws, float* __restrict__ out)
{
    __shared__ __align__(16) float LDS[2 * 32 * 132];   // 33.8 KB union

    const int t   = threadIdx.x;
    const int bid = blockIdx.x;           // 0..1023
    const int which = bid & 1;            // 0 = qk, 1 = v
    const int sub = bid >> 1;             // 0..511
    const int bx = sub & 15;              // col tile
    const int by = sub >> 4;              // row tile 0..31
    const int tx = t & 15, ty = t >> 4;

    const int srow = t >> 1;              // 0..127
    const int kseg = (t & 1) << 4;        // 0 or 16

    const int arow = by * 128 + srow;

    float acc[8][8];
    #pragma unroll
    for (int i = 0; i < 8; ++i)
        #pragma unroll
        for (int j = 0; j < 8; ++j) acc[i][j] = 0.f;

    if (which == 0) {
        // ================= qk path (fp32, argmax-critical) =================
        float (*As)[132] = (float(*)[132])LDS;
        float (*Bs)[132] = (float(*)[132])(LDS + 32 * 132);

        int bsrc;
        {
            const int c = bx * 128 + srow;
            if (c < 1024) bsrc = ((c >> 6) << 7) + (c & 63);
            else          bsrc = 2048 + (((c - 1024) >> 6) << 7) + (c & 63);
        }

        for (int kt = 0; kt < 64; ++kt) {
            const int k0 = kt << 5;
            float4 va[4], vb[4];
            #pragma unroll
            for (int i = 0; i < 4; ++i) {
                va[i] = *(const float4*)(x  + (size_t)arow * KDIM + k0 + kseg + (i << 2));
                vb[i] = *(const float4*)(Wc + (size_t)bsrc * KDIM + k0 + kseg + (i << 2));
            }
            #pragma unroll
            for (int i = 0; i < 4; ++i) {
                const float* pa = (const float*)&va[i];
                const float* pb = (const float*)&vb[i];
                #pragma unroll
                for (int e = 0; e < 4; ++e) {
                    As[kseg + (i << 2) + e][srow] = pa[e];
                    Bs[kseg + (i << 2) + e][srow] = pb[e];
                }
            }
            __syncthreads();

            #pragma unroll
            for (int kk = 0; kk < 32; ++kk) {
                float4 a0 = *(const float4*)(&As[kk][ty << 3]);
                float4 a1 = *(const float4*)(&As[kk][(ty << 3) + 4]);
                float4 b0 = *(const float4*)(&Bs[kk][tx << 2]);
                float4 b1 = *(const float4*)(&Bs[kk][64 + (tx << 2)]);
                const float av[8] = {a0.x, a0.y, a0.z, a0.w, a1.x, a1.y, a1.z, a1.w};
                const float bv[8] = {b0.x, b0.y, b0.z, b0.w, b1.x, b1.y, b1.z, b1.w};
                #pragma unroll
                for (int i = 0; i < 8; ++i)
                    #pragma unroll
                    for (int j = 0; j < 8; ++j)
                        acc[i][j] = fmaf(av[i], bv[j], acc[i][j]);
            }
            __syncthreads();
        }

        float* kout = out + K_OFF;
        #pragma unroll
        for (int i = 0; i < 8; ++i) {
            const int r = by * 128 + (ty << 3) + i;
            const int b = r >> 11, s = r & 2047;
            #pragma unroll
            for (int g = 0; g < 2; ++g) {
                #pragma unroll
                for (int j = 0; j < 4; ++j) {
                    const int c = bx * 128 + (g << 6) + (tx << 2) + j;
                    const float a = acc[i][(g << 2) + j];
                    const int sec = c >> 10;          // 0=q, 1=k
                    const int cc  = c & 1023;
                    const int h = cc >> 6, d2 = cc & 63;
                    const float val = (a + bc[sec * 2048 + h * 128 + d2]) * fq[s * 64 + d2];
                    if (sec == 0) {
                        qws[((size_t)(b * 16 + h) * 2048 + s) * 64 + d2] = 2.0f * val;
                    } else {
                        const size_t o = ((size_t)(b * 16 + h) * 2048 + s) * 128 + d2;
                        kout[o] = val; kout[o + 64] = val;
                    }
                }
            }
        }
    } else {
        // ================= v path (fp16-pair dot2, fp32 accum) =============
        half2v (*As2)[132] = (half2v(*)[132])LDS;
        half2v (*Bs2)[132] = (half2v(*)[132])(LDS + 16 * 132);  // float units

        const int kp0  = (t & 1) << 3;        // pair base 0 or 8
        const int vsrc = 4096 + bx * 128 + srow;

        for (int kt = 0; kt < 64; ++kt) {
            const int k0 = kt << 5;
            float4 va[4], vb[4];
            #pragma unroll
            for (int i = 0; i < 4; ++i) {
                va[i] = *(const float4*)(x  + (size_t)arow * KDIM + k0 + kseg + (i << 2));
                vb[i] = *(const float4*)(Wc + (size_t)vsrc * KDIM + k0 + kseg + (i << 2));
            }
            #pragma unroll
            for (int i = 0; i < 4; ++i) {
                const float* pa = (const float*)&va[i];
                const float* pb = (const float*)&vb[i];
                #pragma unroll
                for (int e = 0; e < 2; ++e) {
                    half2v ha; ha[0] = (_Float16)pa[2 * e]; ha[1] = (_Float16)pa[2 * e + 1];
                    half2v hb; hb[0] = (_Float16)pb[2 * e]; hb[1] = (_Float16)pb[2 * e + 1];
                    As2[kp0 + (i << 1) + e][srow] = ha;
                    Bs2[kp0 + (i << 1) + e][srow] = hb;
                }
            }
            __syncthreads();

            #pragma unroll
            for (int kp = 0; kp < 16; ++kp) {
                uint4 au0 = *reinterpret_cast<const uint4*>(&As2[kp][ty << 3]);
                uint4 au1 = *reinterpret_cast<const uint4*>(&As2[kp][(ty << 3) + 4]);
                const half2v* a2lo = reinterpret_cast<const half2v*>(&au0);
                const half2v* a2hi = reinterpret_cast<const half2v*>(&au1);
                uint4 bu0 = *reinterpret_cast<const uint4*>(&Bs2[kp][tx << 2]);
                uint4 bu1 = *reinterpret_cast<const uint4*>(&Bs2[kp][64 + (tx << 2)]);
                const half2v* b0 = reinterpret_cast<const half2v*>(&bu0);
                const half2v* b1 = reinterpret_cast<const half2v*>(&bu1);
                #pragma unroll
                for (int i = 0; i < 8; ++i) {
                    const half2v ai = (i < 4) ? a2lo[i] : a2hi[i - 4];
                    #pragma unroll
                    for (int j = 0; j < 4; ++j) {
                        acc[i][j]     = fdot2f(ai, b0[j], acc[i][j]);
                        acc[i][4 + j] = fdot2f(ai, b1[j], acc[i][4 + j]);
                    }
                }
            }
            __syncthreads();
        }

        float* vout = out + V_OFF;
        #pragma unroll
        for (int i = 0; i < 8; ++i) {
            const int r = by * 128 + (ty << 3) + i;
            const int b = r >> 11, s = r & 2047;
            #pragma unroll
            for (int g = 0; g < 2; ++g) {
                #pragma unroll
                for (int j = 0; j < 4; ++j) {
                    const int cc = bx * 128 + (g << 6) + (tx << 2) + j;
                    const int h = cc >> 7, d = cc & 127;
                    vout[((size_t)(b * 16 + h) * 2048 + s) * 128 + d] =
                        acc[i][(g << 2) + j] + bc[4096 + cc];
                }
            }
        }
    }
}

// ---------------------------------------------------------------------------
// Kernel 2: register-tiled flash attention, PV via v_dot2_f32_f16
// (unchanged from R12).
// ---------------------------------------------------------------------------
__global__ __launch_bounds__(256, 2) void attn_kernel(
    const float* __restrict__ qws, const float* __restrict__ kbuf,
    const float* __restrict__ vbuf, float* __restrict__ y)
{
    __shared__ __align__(16) float  Qt[64][128];
    __shared__ __align__(16) float  Kt[64][64];
    __shared__ __align__(16) __half Vt[128][64];
    __shared__ __align__(16) __half Ps[4][32][64];

    const int t   = threadIdx.x;
    const int bid = blockIdx.x;
    const int bh  = bid & 31;
    const int qb  = bid >> 5;
    const int tr  = t >> 4;
    const int tc  = t & 15;
    const int s0  = qb << 7;
    const int wid = t >> 6;
    const int ltr = tr & 3;

    const float* qp = qws  + (size_t)bh * (2048 * 64);
    const float* kb = kbuf + (size_t)bh * (2048 * 128);
    const float* vb = vbuf + (size_t)bh * (2048 * 128);

    const int kk0 = t >> 2, sg = t & 3;
    const int kp  = t >> 3;
    const int ds0 = (t & 7) << 4;

    {
        const int qr = t & 127;
        const int dh = (t >> 7) << 5;
        const float* src = qp + (size_t)(s0 + qr) * 64 + dh;
        #pragma unroll
        for (int i = 0; i < 8; ++i) {
            float4 v4 = *(const float4*)(src + (i << 2));
            Qt[dh + (i << 2) + 0][qr] = v4.x;
            Qt[dh + (i << 2) + 1][qr] = v4.y;
            Qt[dh + (i << 2) + 2][qr] = v4.z;
            Qt[dh + (i << 2) + 3][qr] = v4.w;
        }
    }
    {
        #pragma unroll
        for (int i = 0; i < 4; ++i) {
            float4 k4 = *(const float4*)(kb + (size_t)kk0 * 128 + sg * 16 + (i << 2));
            Kt[sg * 16 + (i << 2) + 0][kk0] = k4.x;
            Kt[sg * 16 + (i << 2) + 1][kk0] = k4.y;
            Kt[sg * 16 + (i << 2) + 2][kk0] = k4.z;
            Kt[sg * 16 + (i << 2) + 3][kk0] = k4.w;
        }
        #pragma unroll
        for (int u = 0; u < 4; ++u) {
            float4 v0 = *(const float4*)(vb + (size_t)(2 * kp) * 128 + ds0 + (u << 2));
            float4 v1 = *(const float4*)(vb + (size_t)(2 * kp + 1) * 128 + ds0 + (u << 2));
            const float* p0 = (const float*)&v0;
            const float* p1 = (const float*)&v1;
            #pragma unroll
            for (int e = 0; e < 4; ++e) {
                const int d = ds0 + (u << 2) + e;
                const int off = (2 * kp) ^ (((d >> 2) & 7) << 3);
                half2v h; h[0] = (_Float16)p0[e]; h[1] = (_Float16)p1[e];
                *reinterpret_cast<half2v*>(&Vt[d][off]) = h;
            }
        }
    }
    __syncthreads();

    float accO[8][8];
    #pragma unroll
    for (int i = 0; i < 8; ++i)
        #pragma unroll
        for (int j = 0; j < 8; ++j) accO[i][j] = 0.f;
    float mrow[8], lrow[8];
    #pragma unroll
    for (int i = 0; i < 8; ++i) { mrow[i] = -INFINITY; lrow[i] = 0.f; }

    const float scale = 0.08838834764831845f;  // 1/sqrt(128)
    const int   pvs   = (tc & 7) << 3;
    const int   pss   = ltr << 3;

    for (int kt = 0; kt < 32; ++kt) {
        float4 kreg[4], vr0[4], vr1[4];
        if (kt < 31) {
            const size_t base = (size_t)(kt + 1) * 64 * 128;
            #pragma unroll
            for (int i = 0; i < 4; ++i)
                kreg[i] = *(const float4*)(kb + base + (size_t)kk0 * 128 + sg * 16 + (i << 2));
            #pragma unroll
            for (int u = 0; u < 4; ++u) {
                vr0[u] = *(const float4*)(vb + base + (size_t)(2 * kp) * 128 + ds0 + (u << 2));
                vr1[u] = *(const float4*)(vb + base + (size_t)(2 * kp + 1) * 128 + ds0 + (u << 2));
            }
        }

        float sv[8][4];
        #pragma unroll
        for (int i = 0; i < 8; ++i)
            #pragma unroll
            for (int j = 0; j < 4; ++j) sv[i][j] = 0.f;

        #pragma unroll 4
        for (int d = 0; d < 64; ++d) {
            float4 a0 = *(const float4*)(&Qt[d][tr << 3]);
            float4 a1 = *(const float4*)(&Qt[d][(tr << 3) + 4]);
            float4 kv = *(const float4*)(&Kt[d][tc << 2]);
            const float av[8] = {a0.x, a0.y, a0.z, a0.w, a1.x, a1.y, a1.z, a1.w};
            const float bv[4] = {kv.x, kv.y, kv.z, kv.w};
            #pragma unroll
            for (int i = 0; i < 8; ++i)
                #pragma unroll
                for (int j = 0; j < 4; ++j)
                    sv[i][j] = fmaf(av[i], bv[j], sv[i][j]);
        }

        #pragma unroll
        for (int i = 0; i < 8; ++i) {
            #pragma unroll
            for (int j = 0; j < 4; ++j) sv[i][j] *= scale;
            float mx = fmaxf(fmaxf(sv[i][0], sv[i][1]), fmaxf(sv[i][2], sv[i][3]));
            mx = fmaxf(mx, __shfl_xor(mx, 1));
            mx = fmaxf(mx, __shfl_xor(mx, 2));
            mx = fmaxf(mx, __shfl_xor(mx, 4));
            mx = fmaxf(mx, __shfl_xor(mx, 8));
            if (mx > mrow[i]) {
                const float al = __expf(mrow[i] - mx);
                mrow[i] = mx;
                lrow[i] *= al;
                #pragma unroll
                for (int j = 0; j < 8; ++j) accO[i][j] *= al;
            }
            float ps = 0.f;
            #pragma unroll
            for (int j = 0; j < 4; ++j) {
                const float p = __expf(sv[i][j] - mrow[i]);
                sv[i][j] = p;
                ps += p;
            }
            ps += __shfl_xor(ps, 1);
            ps += __shfl_xor(ps, 2);
            ps += __shfl_xor(ps, 4);
            ps += __shfl_xor(ps, 8);
            lrow[i] += ps;
        }

        #pragma unroll
        for (int i = 0; i < 8; ++i) {
            half2v h0; h0[0] = (_Float16)sv[i][0]; h0[1] = (_Float16)sv[i][1];
            half2v h1; h1[0] = (_Float16)sv[i][2]; h1[1] = (_Float16)sv[i][3];
            uint2 wv;
            wv.x = __builtin_bit_cast(unsigned int, h0);
            wv.y = __builtin_bit_cast(unsigned int, h1);
            *reinterpret_cast<uint2*>(&Ps[wid][(ltr << 3) + i][(tc << 2) ^ pss]) = wv;
        }
        asm volatile("s_waitcnt lgkmcnt(0)" ::: "memory");

        for (int c = 0; c < 8; ++c) {
            uint4 vvu[8];
            #pragma unroll
            for (int e = 0; e < 8; ++e) {
                const int d = (e < 4) ? (tc << 2) + e : 64 + (tc << 2) + (e - 4);
                vvu[e] = *reinterpret_cast<const uint4*>(&Vt[d][(c << 3) ^ pvs]);
            }
            #pragma unroll
            for (int i = 0; i < 8; ++i) {
                uint4 ppu = *reinterpret_cast<const uint4*>(
                    &Ps[wid][(ltr << 3) + i][(c << 3) ^ pss]);
                const half2v* ph = reinterpret_cast<const half2v*>(&ppu);
                #pragma unroll
                for (int e = 0; e < 8; ++e) {
                    const half2v* vh = reinterpret_cast<const half2v*>(&vvu[e]);
                    float a = accO[i][e];
                    a = fdot2f(ph[0], vh[0], a);
                    a = fdot2f(ph[1], vh[1], a);
                    a = fdot2f(ph[2], vh[2], a);
                    a = fdot2f(ph[3], vh[3], a);
                    accO[i][e] = a;
                }
            }
        }

        if (kt < 31) {
            __syncthreads();
            #pragma unroll
            for (int i = 0; i < 4; ++i) {
                Kt[sg * 16 + (i << 2) + 0][kk0] = kreg[i].x;
                Kt[sg * 16 + (i << 2) + 1][kk0] = kreg[i].y;
                Kt[sg * 16 + (i << 2) + 2][kk0] = kreg[i].z;
                Kt[sg * 16 + (i << 2) + 3][kk0] = kreg[i].w;
            }
            #pragma unroll
            for (int u = 0; u < 4; ++u) {
                const float* p0 = (const float*)&vr0[u];
                const float* p1 = (const float*)&vr1[u];
                #pragma unroll
                for (int e = 0; e < 4; ++e) {
                    const int d = ds0 + (u << 2) + e;
                    const int off = (2 * kp) ^ (((d >> 2) & 7) << 3);
                    half2v h; h[0] = (_Float16)p0[e]; h[1] = (_Float16)p1[e];
                    *reinterpret_cast<half2v*>(&Vt[d][off]) = h;
                }
            }
            __syncthreads();
        }
    }

    const int b = bh >> 4, h = bh & 15;
    #pragma unroll
    for (int i = 0; i < 8; ++i) {
        const float inv = 1.f / lrow[i];
        const int srow = s0 + (tr << 3) + i;
        float* yp = y + ((size_t)(b * 2048 + srow)) * 2048 + h * 128;
        float4 o0, o1;
        o0.x = accO[i][0] * inv; o0.y = accO[i][1] * inv;
        o0.z = accO[i][2] * inv; o0.w = accO[i][3] * inv;
        o1.x = accO[i][4] * inv; o1.y = accO[i][5] * inv;
        o1.z = accO[i][6] * inv; o1.w = accO[i][7] * inv;
        *(float4*)(yp + (tc << 2))      = o0;
        *(float4*)(yp + 64 + (tc << 2)) = o1;
    }
}

extern "C" void kernel_launch(void* const* d_in, const int* in_sizes, int n_in,
                              void* d_out, int out_size, void* d_ws, size_t ws_size,
                              hipStream_t stream)
{
    const float* x  = (const float*)d_in[0];
    const float* Wc = (const float*)d_in[1];
    const float* bc = (const float*)d_in[2];
    const float* fq = (const float*)d_in[3];
    float* out = (float*)d_out;
    float* qws = (float*)d_ws;   // compact q, (B,H,S,64) fp32 = 16 MiB

    gemm_merged_kernel<<<1024, 256, 0, stream>>>(x, Wc, bc, fq, qws, out);
    attn_kernel<<<512, 256, 0, stream>>>(qws, out + K_OFF, out + V_OFF, out + Y_OFF);
}